// Round 5
// baseline (806.637 us; speedup 1.0000x reference)
//
#include <hip/hip_runtime.h>
#include <math.h>

#define CD 256

typedef unsigned short u16;
typedef __attribute__((ext_vector_type(8))) short short8;
typedef __attribute__((ext_vector_type(4))) float f32x4;

// Fast sigmoid: native v_exp_f32 (__expf) + v_rcp_f32.
__device__ __forceinline__ float sigmoidf_(float x) {
    return __builtin_amdgcn_rcpf(1.0f + __expf(-x));
}
// Fast gelu (exact erf formulation): Abramowitz-Stegun 7.1.26 rational
// approx, |eps|<=1.5e-7, native exp/rcp.
__device__ __forceinline__ float geluf_(float x) {
    float z = fabsf(x) * 0.70710678118654752f;       // |x|/sqrt(2)
    float t = __builtin_amdgcn_rcpf(__builtin_fmaf(0.3275911f, z, 1.0f));
    float p = t * __builtin_fmaf(t,
                  __builtin_fmaf(t,
                    __builtin_fmaf(t,
                      __builtin_fmaf(t, 1.061405429f, -1.453152027f),
                      1.421413741f),
                    -0.284496736f),
                  0.254829592f);
    float e = __expf(-z * z);
    float erfz = __builtin_fmaf(-p, e, 1.0f);         // erf(|x|/sqrt2) in [0,1)
    float s = (x < 0.0f) ? -erfz : erfz;
    return 0.5f * x * (1.0f + s);
}

__device__ __forceinline__ u16 f2bf(float x) {
    union { float f; unsigned u; } v; v.f = x;
    unsigned r = v.u + 0x7FFF + ((v.u >> 16) & 1);   // RNE
    return (u16)(r >> 16);
}
__device__ __forceinline__ float bf2f(u16 h) {
    union { unsigned u; float f; } v; v.u = ((unsigned)h) << 16;
    return v.f;
}
__device__ __forceinline__ float4 ld_bf4(const u16* p) {
    ushort4 u = *(const ushort4*)p;
    float4 f; f.x = bf2f(u.x); f.y = bf2f(u.y); f.z = bf2f(u.z); f.w = bf2f(u.w);
    return f;
}
__device__ __forceinline__ ushort4 pk_bf4(float4 v) {
    ushort4 u; u.x = f2bf(v.x); u.y = f2bf(v.y); u.z = f2bf(v.z); u.w = f2bf(v.w);
    return u;
}

// ---------------------------------------------------------------------------
// bf16 MFMA GEMM: Y[N,256] = alpha*(A[N,256] @ W) + bias
// A fp32 row-major (converted to bf16 during LDS staging);
// Wt bf16 with Wt[n][k] = W[k][n], read DIRECTLY from global (L2-resident).
// 32-row blocks (r5): acc[2][4] = 32 AGPR halves unified reg use -> ~4
// waves/SIMD instead of 2, and doubles the grid (latency hiding for both
// the gelu staging and the direct-global B loads). Staging uses packed
// 8B LDS writes (4x fewer DS ops than scalar u16).
// Block: 256 thr; wave w owns cols [64w, 64w+64).
// ---------------------------------------------------------------------------
template <int OUT_BF16>
__global__ __launch_bounds__(256) void gemm_mfma(
    const float* __restrict__ A, const u16* __restrict__ Wt,
    const float* __restrict__ bias, float* __restrict__ Yf, u16* __restrict__ Yb,
    int N, float alpha)
{
    __shared__ __align__(16) u16 As[2][32][72];
    const int tid = threadIdx.x;
    const int row0 = blockIdx.x * 32;
    const int wave = tid >> 6, lane = tid & 63;
    const int quad = lane >> 4, l16 = lane & 15;
    f32x4 acc[2][4] = {};   // [mi][ni]

    const int r = tid >> 3, seg = tid & 7;      // 32 rows x 8 col-segments
    int gr = row0 + r; if (gr >= N) gr = N - 1;
    const float* arow = A + (size_t)gr * CD;

    auto stage = [&](int t) {
        const float* ap = arow + t * 64 + seg * 8;
        float4 v0 = *(const float4*)(ap);
        float4 v1 = *(const float4*)(ap + 4);
        *(ushort4*)&As[t & 1][r][seg * 8 + 0] = pk_bf4(v0);
        *(ushort4*)&As[t & 1][r][seg * 8 + 4] = pk_bf4(v1);
    };

    stage(0);
    __syncthreads();
#pragma unroll
    for (int t = 0; t < 4; ++t) {
        if (t < 3) stage(t + 1);
        const u16* wb = Wt + (size_t)(wave * 64 + l16) * CD + t * 64 + quad * 8;
#pragma unroll
        for (int ks = 0; ks < 64; ks += 32) {
            short8 af[2], bf[4];
#pragma unroll
            for (int mi = 0; mi < 2; ++mi)
                af[mi] = *(const short8*)&As[t & 1][mi * 16 + l16][ks + quad * 8];
#pragma unroll
            for (int ni = 0; ni < 4; ++ni)
                bf[ni] = *(const short8*)(wb + (size_t)(ni * 16) * CD + ks);
#pragma unroll
            for (int mi = 0; mi < 2; ++mi)
#pragma unroll
                for (int ni = 0; ni < 4; ++ni)
                    acc[mi][ni] = __builtin_amdgcn_mfma_f32_16x16x32_bf16(
                        af[mi], bf[ni], acc[mi][ni], 0, 0, 0);
        }
        if (t < 3) __syncthreads();
    }
#pragma unroll
    for (int mi = 0; mi < 2; ++mi)
#pragma unroll
        for (int rr = 0; rr < 4; ++rr) {
            int m = mi * 16 + quad * 4 + rr;
            int grow = row0 + m;
            if (grow < N) {
#pragma unroll
                for (int ni = 0; ni < 4; ++ni) {
                    int n = wave * 64 + ni * 16 + l16;
                    float v = alpha * acc[mi][ni][rr] + bias[n];
                    if (OUT_BF16) Yb[(size_t)grow * CD + n] = f2bf(v);
                    else          Yf[(size_t)grow * CD + n] = v;
                }
            }
        }
}

// ---------------------------------------------------------------------------
// ce gate, MFMA: G[r,:] = sigmoid( gelu(ea[col[jb+r],:3]@W1+b1) @ W2 + b2 ), bf16 out
// Same 32-row direct-global-B structure as gemm_mfma.
// ---------------------------------------------------------------------------
__global__ __launch_bounds__(256) void gate_ce_mfma(
    const float* __restrict__ EA, const int* __restrict__ col,
    const float* __restrict__ W1, const float* __restrict__ b1,
    const u16* __restrict__ W2t, const float* __restrict__ b2,
    u16* __restrict__ G, int jb, int count)
{
    __shared__ __align__(16) u16 As[2][32][72];
    const int tid = threadIdx.x;
    const int row0 = blockIdx.x * 32;
    const int wave = tid >> 6, lane = tid & 63;
    const int quad = lane >> 4, l16 = lane & 15;
    f32x4 acc[2][4] = {};

    const int r = tid >> 3, seg = tid & 7;
    int rr0 = row0 + r; if (rr0 >= count) rr0 = count - 1;
    const int e = col[jb + rr0];
    const float a0 = EA[(size_t)e * 3], a1 = EA[(size_t)e * 3 + 1], a2 = EA[(size_t)e * 3 + 2];

    auto stage = [&](int t) {
        int kk = t * 64 + seg * 8;
#pragma unroll
        for (int h = 0; h < 8; h += 4) {
            float4 w0 = *(const float4*)(W1 + kk + h);
            float4 w1 = *(const float4*)(W1 + CD + kk + h);
            float4 w2 = *(const float4*)(W1 + 2 * CD + kk + h);
            float4 bb = *(const float4*)(b1 + kk + h);
            float4 g;
            g.x = geluf_(a0 * w0.x + a1 * w1.x + a2 * w2.x + bb.x);
            g.y = geluf_(a0 * w0.y + a1 * w1.y + a2 * w2.y + bb.y);
            g.z = geluf_(a0 * w0.z + a1 * w1.z + a2 * w2.z + bb.z);
            g.w = geluf_(a0 * w0.w + a1 * w1.w + a2 * w2.w + bb.w);
            *(ushort4*)&As[t & 1][r][seg * 8 + h] = pk_bf4(g);
        }
    };

    stage(0);
    __syncthreads();
#pragma unroll
    for (int t = 0; t < 4; ++t) {
        if (t < 3) stage(t + 1);
        const u16* wb = W2t + (size_t)(wave * 64 + l16) * CD + t * 64 + quad * 8;
#pragma unroll
        for (int ks = 0; ks < 64; ks += 32) {
            short8 af[2], bf[4];
#pragma unroll
            for (int mi = 0; mi < 2; ++mi)
                af[mi] = *(const short8*)&As[t & 1][mi * 16 + l16][ks + quad * 8];
#pragma unroll
            for (int ni = 0; ni < 4; ++ni)
                bf[ni] = *(const short8*)(wb + (size_t)(ni * 16) * CD + ks);
#pragma unroll
            for (int mi = 0; mi < 2; ++mi)
#pragma unroll
                for (int ni = 0; ni < 4; ++ni)
                    acc[mi][ni] = __builtin_amdgcn_mfma_f32_16x16x32_bf16(
                        af[mi], bf[ni], acc[mi][ni], 0, 0, 0);
        }
        if (t < 3) __syncthreads();
    }
#pragma unroll
    for (int mi = 0; mi < 2; ++mi)
#pragma unroll
        for (int rr = 0; rr < 4; ++rr) {
            int m = mi * 16 + quad * 4 + rr;
            int grow = row0 + m;
            if (grow < count) {
#pragma unroll
                for (int ni = 0; ni < 4; ++ni) {
                    int n = wave * 64 + ni * 16 + l16;
                    G[(size_t)grow * CD + n] = f2bf(sigmoidf_(acc[mi][ni][rr] + b2[n]));
                }
            }
        }
}

// ---------------------------------------------------------------------------
// Weight transpose+convert: Wt[n][k] = bf16(W[k][n]) for 12 matrices at once.
// ---------------------------------------------------------------------------
struct WtArgs { const float* src[12]; u16* dst[12]; };

__global__ __launch_bounds__(256) void wtrans_k(WtArgs a)
{
    __shared__ float t[64][65];
    const int mat = blockIdx.y;
    const int tile = blockIdx.x;            // 16 tiles of 64x64
    const int tr = tile >> 2, tc = tile & 3;
    const int r = threadIdx.x >> 2, seg = threadIdx.x & 3;
    const float* S = a.src[mat];
    u16* D = a.dst[mat];
#pragma unroll
    for (int i = 0; i < 16; i += 4) {
        float4 v = *(const float4*)(S + (size_t)(tr * 64 + r) * CD + tc * 64 + seg * 16 + i);
        t[r][seg * 16 + i + 0] = v.x;
        t[r][seg * 16 + i + 1] = v.y;
        t[r][seg * 16 + i + 2] = v.z;
        t[r][seg * 16 + i + 3] = v.w;
    }
    __syncthreads();
#pragma unroll
    for (int i = 0; i < 16; ++i)
        D[(size_t)(tc * 64 + r) * CD + tr * 64 + seg * 16 + i] = f2bf(t[seg * 16 + i][r]);
}

// ---------------------------------------------------------------------------
// Gate lookup tables (cg: 50 combos, cp: 3 phenos), fp32
// ---------------------------------------------------------------------------
__global__ void gate_cg_table_k(const float* __restrict__ embA, const float* __restrict__ embB,
                                const float* __restrict__ Wg, const float* __restrict__ bg,
                                float* __restrict__ tab)
{
    int combo = blockIdx.x;
    int a = combo / 5, b = combo % 5;
    int j = threadIdx.x;
    float s = bg[j];
    for (int k = 0; k < 32; ++k) s += embA[a * 32 + k] * Wg[k * CD + j];
    for (int k = 0; k < 32; ++k) s += embB[b * 32 + k] * Wg[(32 + k) * CD + j];
    tab[(size_t)combo * CD + j] = sigmoidf_(s);
}

__global__ void gate_cp_table_k(const float* __restrict__ embP, const float* __restrict__ Wg,
                                const float* __restrict__ bg, float* __restrict__ tab)
{
    int p = blockIdx.x;
    int j = threadIdx.x;
    float s = bg[j];
    for (int k = 0; k < 32; ++k) s += embP[p * 32 + k] * Wg[k * CD + j];
    tab[(size_t)p * CD + j] = sigmoidf_(s);
}

// ---------------------------------------------------------------------------
// CSR construction. scatter_k additionally materializes, in CSR order:
//   srcidx[pos] = source node of the edge
//   gidx[pos]   = gate-table row (MODE 1: cg combo a*5+b; MODE 2: cp pheno)
//   col[pos]    = edge id (only MODE 3 = ce, which needs gate ordering)
// ---------------------------------------------------------------------------
__global__ void hist_k(const int* __restrict__ ei, int E, int* __restrict__ deg)
{
    int i = blockIdx.x * 256 + threadIdx.x;
    if (i < E) atomicAdd(&deg[ei[E + i]], 1);
}

// 3-phase multi-block exclusive scan over m = n_dst+1 entries of deg -> rowptr.
__global__ __launch_bounds__(256) void scan1_k(const int* __restrict__ deg, int m,
                                               int* __restrict__ blkSum)
{
    __shared__ int ts[256];
    const int tid = threadIdx.x;
    const int base = blockIdx.x * 2048 + tid * 8;
    int s = 0;
#pragma unroll
    for (int i = 0; i < 8; ++i) {
        int idx = base + i;
        s += (idx < m) ? deg[idx] : 0;
    }
    ts[tid] = s;
    __syncthreads();
    for (int off = 128; off > 0; off >>= 1) {
        if (tid < off) ts[tid] += ts[tid + off];
        __syncthreads();
    }
    if (tid == 0) blkSum[blockIdx.x] = ts[0];
}

__global__ __launch_bounds__(64) void scan2_k(int* __restrict__ blkSum, int nblk)
{
    __shared__ int ts[64];
    const int tid = threadIdx.x;
    const int o = (tid < nblk) ? blkSum[tid] : 0;
    ts[tid] = o;
    __syncthreads();
    for (int off = 1; off < 64; off <<= 1) {
        int u = (tid >= off) ? ts[tid - off] : 0;
        __syncthreads();
        ts[tid] += u;
        __syncthreads();
    }
    if (tid < nblk) blkSum[tid] = ts[tid] - o;   // exclusive
}

__global__ __launch_bounds__(256) void scan3_k(const int* __restrict__ deg, int m,
                                               const int* __restrict__ blkSum,
                                               int* __restrict__ rowptr)
{
    __shared__ int ts[256];
    const int tid = threadIdx.x;
    const int base = blockIdx.x * 2048 + tid * 8;
    int v[8];
    int s = 0;
#pragma unroll
    for (int i = 0; i < 8; ++i) {
        int idx = base + i;
        int x = (idx < m) ? deg[idx] : 0;
        v[i] = s;           // exclusive prefix within thread
        s += x;
    }
    ts[tid] = s;
    __syncthreads();
    for (int off = 1; off < 256; off <<= 1) {
        int u = (tid >= off) ? ts[tid - off] : 0;
        __syncthreads();
        ts[tid] += u;
        __syncthreads();
    }
    const int goff = blkSum[blockIdx.x] + ts[tid] - s;
#pragma unroll
    for (int i = 0; i < 8; ++i) {
        int idx = base + i;
        if (idx < m) rowptr[idx] = goff + v[i];
    }
}

// MODE: 0 = gg (srcidx only), 1 = cg (srcidx+gidx), 2 = cp (srcidx+gidx),
//       3 = ce (srcidx+col)
template <int MODE>
__global__ void scatter_k(const int* __restrict__ ei, int E,
                          const int* __restrict__ rowptr, int* __restrict__ cursor,
                          int* __restrict__ col, int* __restrict__ srcidx,
                          int* __restrict__ gidx, const int* __restrict__ eai)
{
    int i = blockIdx.x * 256 + threadIdx.x;
    if (i < E) {
        int d = ei[E + i];
        int pos = rowptr[d] + atomicAdd(&cursor[d], 1);
        srcidx[pos] = ei[i];
        if (MODE == 3) col[pos] = i;
        if (MODE == 1) gidx[pos] = eai[2 * i] * 5 + eai[2 * i + 1];
        if (MODE == 2) gidx[pos] = eai[i];
    }
}

// ---------------------------------------------------------------------------
// Destination-major aggregation (bf16 proj, fp32 gate tables, fp32 out)
// GATED: 0 = no gate (gg), 1 = fp32 gate table indexed by gidx (cg/cp)
// ADDIN: rmw aggr row.
// 4-wide predicated unroll: 4 independent Psrc gathers in flight per wave.
// ---------------------------------------------------------------------------
template <int GATED, int ADDIN>
__global__ __launch_bounds__(256) void dest_aggr(
    const u16* __restrict__ Psrc, const u16* __restrict__ Pdst,
    const int* __restrict__ srcidx, const int* __restrict__ gidx,
    const int* __restrict__ rowptr, const float* __restrict__ gate,
    float* __restrict__ aggr, int n_dst)
{
    const int d = blockIdx.x * 4 + (threadIdx.x >> 6);
    if (d >= n_dst) return;
    const int lane = threadIdx.x & 63;
    const int js = rowptr[d], je = rowptr[d + 1];
    const float4 dv = ld_bf4(Pdst + (size_t)d * CD + lane * 4);   // issued early
    float4 accS = {0.f, 0.f, 0.f, 0.f};
    float4 accG = {0.f, 0.f, 0.f, 0.f};
    const int jn = je - 1;
    for (int j = js; j < je; j += 4) {
        const int j1 = (j + 1 > jn) ? jn : j + 1;
        const int j2 = (j + 2 > jn) ? jn : j + 2;
        const int j3 = (j + 3 > jn) ? jn : j + 3;
        const float m1 = (j + 1 <= jn) ? 1.f : 0.f;
        const float m2 = (j + 2 <= jn) ? 1.f : 0.f;
        const float m3 = (j + 3 <= jn) ? 1.f : 0.f;
        const int s0 = srcidx[j], s1 = srcidx[j1], s2 = srcidx[j2], s3 = srcidx[j3];
        float4 a0 = ld_bf4(Psrc + (size_t)s0 * CD + lane * 4);
        float4 a1 = ld_bf4(Psrc + (size_t)s1 * CD + lane * 4);
        float4 a2 = ld_bf4(Psrc + (size_t)s2 * CD + lane * 4);
        float4 a3 = ld_bf4(Psrc + (size_t)s3 * CD + lane * 4);
        if (GATED) {
            const int g0 = gidx[j], g1 = gidx[j1], g2 = gidx[j2], g3 = gidx[j3];
            float4 q0 = *(const float4*)(gate + (size_t)g0 * CD + lane * 4);
            float4 q1 = *(const float4*)(gate + (size_t)g1 * CD + lane * 4);
            float4 q2 = *(const float4*)(gate + (size_t)g2 * CD + lane * 4);
            float4 q3 = *(const float4*)(gate + (size_t)g3 * CD + lane * 4);
            q1.x *= m1; q1.y *= m1; q1.z *= m1; q1.w *= m1;
            q2.x *= m2; q2.y *= m2; q2.z *= m2; q2.w *= m2;
            q3.x *= m3; q3.y *= m3; q3.z *= m3; q3.w *= m3;
            accS.x += q0.x * a0.x + q1.x * a1.x + q2.x * a2.x + q3.x * a3.x;
            accS.y += q0.y * a0.y + q1.y * a1.y + q2.y * a2.y + q3.y * a3.y;
            accS.z += q0.z * a0.z + q1.z * a1.z + q2.z * a2.z + q3.z * a3.z;
            accS.w += q0.w * a0.w + q1.w * a1.w + q2.w * a2.w + q3.w * a3.w;
            accG.x += q0.x + q1.x + q2.x + q3.x;
            accG.y += q0.y + q1.y + q2.y + q3.y;
            accG.z += q0.z + q1.z + q2.z + q3.z;
            accG.w += q0.w + q1.w + q2.w + q3.w;
        } else {
            accS.x += a0.x + m1 * a1.x + m2 * a2.x + m3 * a3.x;
            accS.y += a0.y + m1 * a1.y + m2 * a2.y + m3 * a3.y;
            accS.z += a0.z + m1 * a1.z + m2 * a2.z + m3 * a3.z;
            accS.w += a0.w + m1 * a1.w + m2 * a2.w + m3 * a3.w;
        }
    }
    const float cnt = (float)(je - js);
    float4 r;
    if (GATED) {
        r.x = accS.x + accG.x * dv.x; r.y = accS.y + accG.y * dv.y;
        r.z = accS.z + accG.z * dv.z; r.w = accS.w + accG.w * dv.w;
    } else {
        r.x = accS.x + cnt * dv.x; r.y = accS.y + cnt * dv.y;
        r.z = accS.z + cnt * dv.z; r.w = accS.w + cnt * dv.w;
    }
    float* ap = aggr + (size_t)d * CD + lane * 4;
    if (ADDIN) {
        float4 old = *(const float4*)ap;
        r.x += old.x; r.y += old.y; r.z += old.z; r.w += old.w;
    }
    *(float4*)ap = r;
}

// ce: bf16 gate buffer in CSR order, j-window [jb, jend).
// ATOMIC=1: partial window, accumulate with atomics (needs pre-zeroed aggr).
// ATOMIC=0: full coverage in one chunk -> plain store (zero rows included).
template <int ATOMIC>
__global__ __launch_bounds__(256) void ce_aggr_chunk(
    const u16* __restrict__ Psrc, const u16* __restrict__ Pdst,
    const int* __restrict__ srcidx,
    const int* __restrict__ rowptr,
    const u16* __restrict__ G,
    float* __restrict__ aggr, int n_dst, int jb, int jend)
{
    const int d = blockIdx.x * 4 + (threadIdx.x >> 6);
    if (d >= n_dst) return;
    const int lane = threadIdx.x & 63;
    int lo = rowptr[d];     if (lo < jb)   lo = jb;
    int hi = rowptr[d + 1]; if (hi > jend) hi = jend;
    if (ATOMIC && lo >= hi) return;
    const float4 dv = ld_bf4(Pdst + (size_t)d * CD + lane * 4);
    float4 accS = {0.f, 0.f, 0.f, 0.f};
    float4 accG = {0.f, 0.f, 0.f, 0.f};
    const int jn = hi - 1;
    for (int j = lo; j < hi; j += 4) {
        const int j1 = (j + 1 > jn) ? jn : j + 1;
        const int j2 = (j + 2 > jn) ? jn : j + 2;
        const int j3 = (j + 3 > jn) ? jn : j + 3;
        const float m1 = (j + 1 <= jn) ? 1.f : 0.f;
        const float m2 = (j + 2 <= jn) ? 1.f : 0.f;
        const float m3 = (j + 3 <= jn) ? 1.f : 0.f;
        const int s0 = srcidx[j], s1 = srcidx[j1], s2 = srcidx[j2], s3 = srcidx[j3];
        float4 a0 = ld_bf4(Psrc + (size_t)s0 * CD + lane * 4);
        float4 a1 = ld_bf4(Psrc + (size_t)s1 * CD + lane * 4);
        float4 a2 = ld_bf4(Psrc + (size_t)s2 * CD + lane * 4);
        float4 a3 = ld_bf4(Psrc + (size_t)s3 * CD + lane * 4);
        float4 q0 = ld_bf4(G + (size_t)(j  - jb) * CD + lane * 4);
        float4 q1 = ld_bf4(G + (size_t)(j1 - jb) * CD + lane * 4);
        float4 q2 = ld_bf4(G + (size_t)(j2 - jb) * CD + lane * 4);
        float4 q3 = ld_bf4(G + (size_t)(j3 - jb) * CD + lane * 4);
        q1.x *= m1; q1.y *= m1; q1.z *= m1; q1.w *= m1;
        q2.x *= m2; q2.y *= m2; q2.z *= m2; q2.w *= m2;
        q3.x *= m3; q3.y *= m3; q3.z *= m3; q3.w *= m3;
        accS.x += q0.x * a0.x + q1.x * a1.x + q2.x * a2.x + q3.x * a3.x;
        accS.y += q0.y * a0.y + q1.y * a1.y + q2.y * a2.y + q3.y * a3.y;
        accS.z += q0.z * a0.z + q1.z * a1.z + q2.z * a2.z + q3.z * a3.z;
        accS.w += q0.w * a0.w + q1.w * a1.w + q2.w * a2.w + q3.w * a3.w;
        accG.x += q0.x + q1.x + q2.x + q3.x;
        accG.y += q0.y + q1.y + q2.y + q3.y;
        accG.z += q0.z + q1.z + q2.z + q3.z;
        accG.w += q0.w + q1.w + q2.w + q3.w;
    }
    float* ap = aggr + (size_t)d * CD + lane * 4;
    if (ATOMIC) {
        atomicAdd(ap + 0, accS.x + accG.x * dv.x);
        atomicAdd(ap + 1, accS.y + accG.y * dv.y);
        atomicAdd(ap + 2, accS.z + accG.z * dv.z);
        atomicAdd(ap + 3, accS.w + accG.w * dv.w);
    } else {
        float4 r;
        r.x = accS.x + accG.x * dv.x; r.y = accS.y + accG.y * dv.y;
        r.z = accS.z + accG.z * dv.z; r.w = accS.w + accG.w * dv.w;
        *(float4*)ap = r;
    }
}

// ---------------------------------------------------------------------------
extern "C" void kernel_launch(void* const* d_in, const int* in_sizes, int n_in,
                              void* d_out, int out_size, void* d_ws, size_t ws_size,
                              hipStream_t stream)
{
    const float* x_chem = (const float*)d_in[0];
    const float* x_gene = (const float*)d_in[1];
    const float* x_go   = (const float*)d_in[2];
    const float* x_pw   = (const float*)d_in[3];
    const int*   ei_cg  = (const int*)d_in[4];
    const int*   ei_cp  = (const int*)d_in[5];
    const int*   ei_ce  = (const int*)d_in[6];
    const int*   ei_gg  = (const int*)d_in[7];
    const int*   ea_cg  = (const int*)d_in[8];
    const int*   ea_cp  = (const int*)d_in[9];
    const float* ea_ce  = (const float*)d_in[10];

    const float* W_src_cg = (const float*)d_in[11];
    const float* b_src_cg = (const float*)d_in[12];
    const float* W_dst_cg = (const float*)d_in[13];
    const float* b_dst_cg = (const float*)d_in[14];
    const float* W_src_cp = (const float*)d_in[16];
    const float* b_src_cp = (const float*)d_in[17];
    const float* W_dst_cp = (const float*)d_in[18];
    const float* b_dst_cp = (const float*)d_in[19];
    const float* W_src_ce = (const float*)d_in[21];
    const float* b_src_ce = (const float*)d_in[22];
    const float* W_dst_ce = (const float*)d_in[23];
    const float* b_dst_ce = (const float*)d_in[24];
    const float* W_src_gg = (const float*)d_in[26];
    const float* b_src_gg = (const float*)d_in[27];
    const float* W_dst_gg = (const float*)d_in[28];
    const float* b_dst_gg = (const float*)d_in[29];

    const float* emb_at   = (const float*)d_in[31];
    const float* emb_as   = (const float*)d_in[32];
    const float* W_gate_cg = (const float*)d_in[33];
    const float* b_gate_cg = (const float*)d_in[34];
    const float* emb_ph   = (const float*)d_in[35];
    const float* W_gate_cp = (const float*)d_in[36];
    const float* b_gate_cp = (const float*)d_in[37];
    const float* W_gate1_ce = (const float*)d_in[38];
    const float* b_gate1_ce = (const float*)d_in[39];
    const float* W_gate2_ce = (const float*)d_in[40];
    const float* b_gate2_ce = (const float*)d_in[41];
    const float* W_out_gene = (const float*)d_in[42];
    const float* b_out_gene = (const float*)d_in[43];
    const float* W_out_go   = (const float*)d_in[44];
    const float* b_out_go   = (const float*)d_in[45];
    const float* W_out_pw   = (const float*)d_in[46];
    const float* b_out_pw   = (const float*)d_in[47];

    const int Nc  = in_sizes[0] / CD;
    const int Ng  = in_sizes[1] / CD;
    const int Ngo = in_sizes[2] / CD;
    const int Np  = in_sizes[3] / CD;
    const int E   = in_sizes[4] / 2;

    // ---- workspace layout (float units) ----
    float* ws = (float*)d_ws;
    size_t off = 0;
    float* aggr_gene = ws + off; off += (size_t)Ng  * CD;
    float* aggr_go   = ws + off; off += (size_t)Ngo * CD;
    float* aggr_pw   = ws + off; off += (size_t)Np  * CD;   // aggr_* contiguous
    int maxSrc = (Nc > Ng) ? Nc : Ng;
    int maxDst = Ng; if (Ngo > maxDst) maxDst = Ngo; if (Np > maxDst) maxDst = Np;
    u16* projb_src = (u16*)(ws + off); off += (size_t)maxSrc * CD / 2;
    u16* projb_dst = (u16*)(ws + off); off += (size_t)maxDst * CD / 2;
    u16* wt_all    = (u16*)(ws + off); off += (size_t)12 * CD * CD / 2;
    float* gtab_cg = ws + off; off += 50 * CD;
    float* gtab_cp = ws + off; off += 3 * CD;
    // CSR ints (+ CSR-ordered srcidx/gidx + scan block sums)
    int* deg    = (int*)(ws + off);
    int* cursor = deg + (maxDst + 1);
    int* rowptr = cursor + (maxDst + 1);
    int* colv   = rowptr + (maxDst + 2);
    int* srcidx = colv + E;
    int* gidx   = srcidx + E;
    int* blkSum = gidx + E;
    {
        size_t ints = 2 * (size_t)(maxDst + 1) + (size_t)(maxDst + 2) + 3 * (size_t)E + 64;
        off += (ints + 3) & ~(size_t)3;
    }
    // remaining -> bf16 ce gate buffer (CSR-ordered); one row = 128 floats.
    u16* gate_ce = (u16*)(ws + off);
    long long remaining = (long long)(ws_size / 4) - (long long)off;
    if (remaining < 0) remaining = 0;
    long long CHUNKll = remaining / 128;
    if (CHUNKll > E) CHUNKll = E;
    int CHUNK = (int)CHUNKll;
    if (CHUNK < 1) CHUNK = 1;

    float* out_gene = (float*)d_out + (size_t)Nc * CD;
    float* out_go   = out_gene + (size_t)Ng * CD;
    float* out_pw   = out_go + (size_t)Ngo * CD;

    const int EB = (E + 255) / 256;

    auto gemm_bf = [&](const float* A, const u16* Wt, const float* b, u16* Y, int N) {
        gemm_mfma<1><<<(N + 31) / 32, 256, 0, stream>>>(A, Wt, b, nullptr, Y, N, 1.0f);
    };
    auto gemm_f = [&](const float* A, const u16* Wt, const float* b, float* Y, int N, float alpha) {
        gemm_mfma<0><<<(N + 31) / 32, 256, 0, stream>>>(A, Wt, b, Y, nullptr, N, alpha);
    };
    auto build_csr = [&](const int* ei, int n_dst, int mode, const int* eai) {
        hipMemsetAsync(deg, 0, 2 * (size_t)(maxDst + 1) * sizeof(int), stream);
        hist_k<<<EB, 256, 0, stream>>>(ei, E, deg);
        const int m = n_dst + 1;
        const int nblk = (m + 2047) / 2048;
        scan1_k<<<nblk, 256, 0, stream>>>(deg, m, blkSum);
        scan2_k<<<1, 64, 0, stream>>>(blkSum, nblk);
        scan3_k<<<nblk, 256, 0, stream>>>(deg, m, blkSum, rowptr);
        if (mode == 1)
            scatter_k<1><<<EB, 256, 0, stream>>>(ei, E, rowptr, cursor, colv, srcidx, gidx, eai);
        else if (mode == 2)
            scatter_k<2><<<EB, 256, 0, stream>>>(ei, E, rowptr, cursor, colv, srcidx, gidx, eai);
        else if (mode == 3)
            scatter_k<3><<<EB, 256, 0, stream>>>(ei, E, rowptr, cursor, colv, srcidx, nullptr, nullptr);
        else
            scatter_k<0><<<EB, 256, 0, stream>>>(ei, E, rowptr, cursor, colv, srcidx, nullptr, nullptr);
    };

    // 1) passthrough copy
    hipMemcpyAsync(d_out, x_chem, (size_t)Nc * CD * sizeof(float),
                   hipMemcpyDeviceToDevice, stream);

    // 2) weight transpose+convert (12 C x C matrices -> bf16 Wt[n][k])
    u16* Wt_src_cg = wt_all + 0 * CD * CD;  u16* Wt_dst_cg = wt_all + 1 * CD * CD;
    u16* Wt_src_cp = wt_all + 2 * CD * CD;  u16* Wt_dst_cp = wt_all + 3 * CD * CD;
    u16* Wt_src_ce = wt_all + 4 * CD * CD;  u16* Wt_dst_ce = wt_all + 5 * CD * CD;
    u16* Wt_src_gg = wt_all + 6 * CD * CD;  u16* Wt_dst_gg = wt_all + 7 * CD * CD;
    u16* Wt_g2_ce  = wt_all + 8 * CD * CD;
    u16* Wt_o_gene = wt_all + 9 * CD * CD;  u16* Wt_o_go = wt_all + 10 * CD * CD;
    u16* Wt_o_pw   = wt_all + 11 * CD * CD;
    {
        WtArgs wa;
        const float* s[12] = {W_src_cg, W_dst_cg, W_src_cp, W_dst_cp, W_src_ce, W_dst_ce,
                              W_src_gg, W_dst_gg, W_gate2_ce, W_out_gene, W_out_go, W_out_pw};
        u16* dpt[12] = {Wt_src_cg, Wt_dst_cg, Wt_src_cp, Wt_dst_cp, Wt_src_ce, Wt_dst_ce,
                        Wt_src_gg, Wt_dst_gg, Wt_g2_ce, Wt_o_gene, Wt_o_go, Wt_o_pw};
        for (int i = 0; i < 12; ++i) { wa.src[i] = s[i]; wa.dst[i] = dpt[i]; }
        wtrans_k<<<dim3(16, 12), 256, 0, stream>>>(wa);
    }

    // 3) gate tables
    gate_cg_table_k<<<50, 256, 0, stream>>>(emb_at, emb_as, W_gate_cg, b_gate_cg, gtab_cg);
    gate_cp_table_k<<<3, 256, 0, stream>>>(emb_ph, W_gate_cp, b_gate_cp, gtab_cp);

    // 4) cg: chemical -> gene (store into aggr_gene)
    gemm_bf(x_chem, Wt_src_cg, b_src_cg, projb_src, Nc);
    gemm_bf(x_gene, Wt_dst_cg, b_dst_cg, projb_dst, Ng);
    build_csr(ei_cg, Ng, 1, ea_cg);
    dest_aggr<1, 0><<<(Ng + 3) / 4, 256, 0, stream>>>(projb_src, projb_dst, srcidx, gidx,
                                                      rowptr, gtab_cg, aggr_gene, Ng);

    // 5) cp: chemical -> go_term
    gemm_bf(x_chem, Wt_src_cp, b_src_cp, projb_src, Nc);
    gemm_bf(x_go,   Wt_dst_cp, b_dst_cp, projb_dst, Ngo);
    build_csr(ei_cp, Ngo, 2, ea_cp);
    dest_aggr<1, 0><<<(Ngo + 3) / 4, 256, 0, stream>>>(projb_src, projb_dst, srcidx, gidx,
                                                       rowptr, gtab_cp, aggr_go, Ngo);

    // 6) ce: chemical -> pathway (continuous gate, CSR-ordered bf16 chunks).
    gemm_bf(x_chem, Wt_src_ce, b_src_ce, projb_src, Nc);
    gemm_bf(x_pw,   Wt_dst_ce, b_dst_ce, projb_dst, Np);
    build_csr(ei_ce, Np, 3, nullptr);
    if (CHUNK >= E) {
        gate_ce_mfma<<<(E + 31) / 32, 256, 0, stream>>>(ea_ce, colv, W_gate1_ce, b_gate1_ce,
                                                        Wt_g2_ce, b_gate2_ce, gate_ce, 0, E);
        ce_aggr_chunk<0><<<(Np + 3) / 4, 256, 0, stream>>>(projb_src, projb_dst, srcidx,
                                                           rowptr, gate_ce,
                                                           aggr_pw, Np, 0, E);
    } else {
        hipMemsetAsync(aggr_pw, 0, (size_t)Np * CD * sizeof(float), stream);
        for (int jb = 0; jb < E; jb += CHUNK) {
            int cnt = E - jb; if (cnt > CHUNK) cnt = CHUNK;
            gate_ce_mfma<<<(cnt + 31) / 32, 256, 0, stream>>>(ea_ce, colv, W_gate1_ce, b_gate1_ce,
                                                              Wt_g2_ce, b_gate2_ce, gate_ce, jb, cnt);
            ce_aggr_chunk<1><<<(Np + 3) / 4, 256, 0, stream>>>(projb_src, projb_dst, srcidx,
                                                               rowptr, gate_ce,
                                                               aggr_pw, Np, jb, jb + cnt);
        }
    }

    // 7) gg: gene -> gene (no gate), read-add-store into aggr_gene
    gemm_bf(x_gene, Wt_src_gg, b_src_gg, projb_src, Ng);
    gemm_bf(x_gene, Wt_dst_gg, b_dst_gg, projb_dst, Ng);
    build_csr(ei_gg, Ng, 0, nullptr);
    dest_aggr<0, 1><<<(Ng + 3) / 4, 256, 0, stream>>>(projb_src, projb_dst, srcidx, nullptr,
                                                      rowptr, nullptr, aggr_gene, Ng);

    // 8) output heads straight from fp32 aggr (alpha folds attention 0.25; gene
    //    branch additionally has the 0.5 from 0.5*(aggr_cg+aggr_gg))
    gemm_f(aggr_gene, Wt_o_gene, b_out_gene, out_gene, Ng,  0.125f);
    gemm_f(aggr_go,   Wt_o_go,   b_out_go,   out_go,   Ngo, 0.25f);
    gemm_f(aggr_pw,   Wt_o_pw,   b_out_pw,   out_pw,   Np,  0.25f);
}

// Round 6
// 682.912 us; speedup vs baseline: 1.1812x; 1.1812x over previous
//
#include <hip/hip_runtime.h>
#include <math.h>

#define CD 256
#define NG 17            // ce gate grid points per axis (step 1/16)
#define NG3 (NG * NG * NG)

typedef unsigned short u16;
typedef __attribute__((ext_vector_type(8))) short short8;
typedef __attribute__((ext_vector_type(4))) float f32x4;

// Fast sigmoid: native v_exp_f32 (__expf) + v_rcp_f32.
__device__ __forceinline__ float sigmoidf_(float x) {
    return __builtin_amdgcn_rcpf(1.0f + __expf(-x));
}
// Fast gelu (exact erf formulation): Abramowitz-Stegun 7.1.26 rational
// approx, |eps|<=1.5e-7, native exp/rcp.
__device__ __forceinline__ float geluf_(float x) {
    float z = fabsf(x) * 0.70710678118654752f;       // |x|/sqrt(2)
    float t = __builtin_amdgcn_rcpf(__builtin_fmaf(0.3275911f, z, 1.0f));
    float p = t * __builtin_fmaf(t,
                  __builtin_fmaf(t,
                    __builtin_fmaf(t,
                      __builtin_fmaf(t, 1.061405429f, -1.453152027f),
                      1.421413741f),
                    -0.284496736f),
                  0.254829592f);
    float e = __expf(-z * z);
    float erfz = __builtin_fmaf(-p, e, 1.0f);         // erf(|x|/sqrt2) in [0,1)
    float s = (x < 0.0f) ? -erfz : erfz;
    return 0.5f * x * (1.0f + s);
}

__device__ __forceinline__ u16 f2bf(float x) {
    union { float f; unsigned u; } v; v.f = x;
    unsigned r = v.u + 0x7FFF + ((v.u >> 16) & 1);   // RNE
    return (u16)(r >> 16);
}
__device__ __forceinline__ float bf2f(u16 h) {
    union { unsigned u; float f; } v; v.u = ((unsigned)h) << 16;
    return v.f;
}
__device__ __forceinline__ float4 ld_bf4(const u16* p) {
    ushort4 u = *(const ushort4*)p;
    float4 f; f.x = bf2f(u.x); f.y = bf2f(u.y); f.z = bf2f(u.z); f.w = bf2f(u.w);
    return f;
}
__device__ __forceinline__ ushort4 pk_bf4(float4 v) {
    ushort4 u; u.x = f2bf(v.x); u.y = f2bf(v.y); u.z = f2bf(v.z); u.w = f2bf(v.w);
    return u;
}

// ---------------------------------------------------------------------------
// bf16 MFMA GEMM: Y[N,256] = act( alpha*(A[N,256] @ W) + bias )
// A fp32 row-major (converted to bf16 during LDS staging);
// Wt bf16 with Wt[n][k] = W[k][n], read DIRECTLY from global (L2-resident).
// ACT: 0 = none, 1 = sigmoid (used for the ce gate table).
// 32-row blocks; wave w owns cols [64w, 64w+64).
// ---------------------------------------------------------------------------
template <int OUT_BF16, int ACT>
__global__ __launch_bounds__(256) void gemm_mfma(
    const float* __restrict__ A, const u16* __restrict__ Wt,
    const float* __restrict__ bias, float* __restrict__ Yf, u16* __restrict__ Yb,
    int N, float alpha)
{
    __shared__ __align__(16) u16 As[2][32][72];
    const int tid = threadIdx.x;
    const int row0 = blockIdx.x * 32;
    const int wave = tid >> 6, lane = tid & 63;
    const int quad = lane >> 4, l16 = lane & 15;
    f32x4 acc[2][4] = {};   // [mi][ni]

    const int r = tid >> 3, seg = tid & 7;      // 32 rows x 8 col-segments
    int gr = row0 + r; if (gr >= N) gr = N - 1;
    const float* arow = A + (size_t)gr * CD;

    auto stage = [&](int t) {
        const float* ap = arow + t * 64 + seg * 8;
        float4 v0 = *(const float4*)(ap);
        float4 v1 = *(const float4*)(ap + 4);
        *(ushort4*)&As[t & 1][r][seg * 8 + 0] = pk_bf4(v0);
        *(ushort4*)&As[t & 1][r][seg * 8 + 4] = pk_bf4(v1);
    };

    stage(0);
    __syncthreads();
#pragma unroll
    for (int t = 0; t < 4; ++t) {
        if (t < 3) stage(t + 1);
        const u16* wb = Wt + (size_t)(wave * 64 + l16) * CD + t * 64 + quad * 8;
#pragma unroll
        for (int ks = 0; ks < 64; ks += 32) {
            short8 af[2], bf[4];
#pragma unroll
            for (int mi = 0; mi < 2; ++mi)
                af[mi] = *(const short8*)&As[t & 1][mi * 16 + l16][ks + quad * 8];
#pragma unroll
            for (int ni = 0; ni < 4; ++ni)
                bf[ni] = *(const short8*)(wb + (size_t)(ni * 16) * CD + ks);
#pragma unroll
            for (int mi = 0; mi < 2; ++mi)
#pragma unroll
                for (int ni = 0; ni < 4; ++ni)
                    acc[mi][ni] = __builtin_amdgcn_mfma_f32_16x16x32_bf16(
                        af[mi], bf[ni], acc[mi][ni], 0, 0, 0);
        }
        if (t < 3) __syncthreads();
    }
#pragma unroll
    for (int mi = 0; mi < 2; ++mi)
#pragma unroll
        for (int rr = 0; rr < 4; ++rr) {
            int m = mi * 16 + quad * 4 + rr;
            int grow = row0 + m;
            if (grow < N) {
#pragma unroll
                for (int ni = 0; ni < 4; ++ni) {
                    int n = wave * 64 + ni * 16 + l16;
                    float v = alpha * acc[mi][ni][rr] + bias[n];
                    if (ACT) v = sigmoidf_(v);
                    if (OUT_BF16) Yb[(size_t)grow * CD + n] = f2bf(v);
                    else          Yf[(size_t)grow * CD + n] = v;
                }
            }
        }
}

// ---------------------------------------------------------------------------
// ce gate table, step 1: H[c,:] = gelu( grid(c) @ W1 + b1 ), fp32.
// c = (ix*NG + iy)*NG + iz, grid = (ix,iy,iz)/16. 4913 rows.
// Step 2 is gemm_mfma<0,1> (sigmoid epilogue) with the pre-transposed W2t.
// ---------------------------------------------------------------------------
__global__ __launch_bounds__(256) void build_h_ce_k(
    const float* __restrict__ W1, const float* __restrict__ b1,
    float* __restrict__ H)
{
    const int c = blockIdx.x;
    const int iz = c % NG, iy = (c / NG) % NG, ix = c / (NG * NG);
    const float a0 = ix * 0.0625f, a1 = iy * 0.0625f, a2 = iz * 0.0625f;
    const int j = threadIdx.x;
    float v = __builtin_fmaf(a0, W1[j],
              __builtin_fmaf(a1, W1[CD + j],
              __builtin_fmaf(a2, W1[2 * CD + j], b1[j])));
    H[(size_t)c * CD + j] = geluf_(v);
}

// ---------------------------------------------------------------------------
// Weight transpose+convert: Wt[n][k] = bf16(W[k][n]) for 12 matrices at once.
// ---------------------------------------------------------------------------
struct WtArgs { const float* src[12]; u16* dst[12]; };

__global__ __launch_bounds__(256) void wtrans_k(WtArgs a)
{
    __shared__ float t[64][65];
    const int mat = blockIdx.y;
    const int tile = blockIdx.x;            // 16 tiles of 64x64
    const int tr = tile >> 2, tc = tile & 3;
    const int r = threadIdx.x >> 2, seg = threadIdx.x & 3;
    const float* S = a.src[mat];
    u16* D = a.dst[mat];
#pragma unroll
    for (int i = 0; i < 16; i += 4) {
        float4 v = *(const float4*)(S + (size_t)(tr * 64 + r) * CD + tc * 64 + seg * 16 + i);
        t[r][seg * 16 + i + 0] = v.x;
        t[r][seg * 16 + i + 1] = v.y;
        t[r][seg * 16 + i + 2] = v.z;
        t[r][seg * 16 + i + 3] = v.w;
    }
    __syncthreads();
#pragma unroll
    for (int i = 0; i < 16; ++i)
        D[(size_t)(tc * 64 + r) * CD + tr * 64 + seg * 16 + i] = f2bf(t[seg * 16 + i][r]);
}

// ---------------------------------------------------------------------------
// Gate lookup tables (cg: 50 combos, cp: 3 phenos), fp32
// ---------------------------------------------------------------------------
__global__ void gate_cg_table_k(const float* __restrict__ embA, const float* __restrict__ embB,
                                const float* __restrict__ Wg, const float* __restrict__ bg,
                                float* __restrict__ tab)
{
    int combo = blockIdx.x;
    int a = combo / 5, b = combo % 5;
    int j = threadIdx.x;
    float s = bg[j];
    for (int k = 0; k < 32; ++k) s += embA[a * 32 + k] * Wg[k * CD + j];
    for (int k = 0; k < 32; ++k) s += embB[b * 32 + k] * Wg[(32 + k) * CD + j];
    tab[(size_t)combo * CD + j] = sigmoidf_(s);
}

__global__ void gate_cp_table_k(const float* __restrict__ embP, const float* __restrict__ Wg,
                                const float* __restrict__ bg, float* __restrict__ tab)
{
    int p = blockIdx.x;
    int j = threadIdx.x;
    float s = bg[j];
    for (int k = 0; k < 32; ++k) s += embP[p * 32 + k] * Wg[k * CD + j];
    tab[(size_t)p * CD + j] = sigmoidf_(s);
}

// ---------------------------------------------------------------------------
// CSR construction. scatter_k materializes, in CSR order:
//   srcidx[pos] = source node of the edge
//   gidx[pos]   = gate-table row:
//     MODE 1: cg combo a*5+b        (eai pairs)
//     MODE 2: cp pheno               (eai scalar)
//     MODE 3: ce nearest grid point  (eaf triples -> 17^3 index)
// ---------------------------------------------------------------------------
__global__ void hist_k(const int* __restrict__ ei, int E, int* __restrict__ deg)
{
    int i = blockIdx.x * 256 + threadIdx.x;
    if (i < E) atomicAdd(&deg[ei[E + i]], 1);
}

// 3-phase multi-block exclusive scan over m = n_dst+1 entries of deg -> rowptr.
__global__ __launch_bounds__(256) void scan1_k(const int* __restrict__ deg, int m,
                                               int* __restrict__ blkSum)
{
    __shared__ int ts[256];
    const int tid = threadIdx.x;
    const int base = blockIdx.x * 2048 + tid * 8;
    int s = 0;
#pragma unroll
    for (int i = 0; i < 8; ++i) {
        int idx = base + i;
        s += (idx < m) ? deg[idx] : 0;
    }
    ts[tid] = s;
    __syncthreads();
    for (int off = 128; off > 0; off >>= 1) {
        if (tid < off) ts[tid] += ts[tid + off];
        __syncthreads();
    }
    if (tid == 0) blkSum[blockIdx.x] = ts[0];
}

__global__ __launch_bounds__(64) void scan2_k(int* __restrict__ blkSum, int nblk)
{
    __shared__ int ts[64];
    const int tid = threadIdx.x;
    const int o = (tid < nblk) ? blkSum[tid] : 0;
    ts[tid] = o;
    __syncthreads();
    for (int off = 1; off < 64; off <<= 1) {
        int u = (tid >= off) ? ts[tid - off] : 0;
        __syncthreads();
        ts[tid] += u;
        __syncthreads();
    }
    if (tid < nblk) blkSum[tid] = ts[tid] - o;   // exclusive
}

__global__ __launch_bounds__(256) void scan3_k(const int* __restrict__ deg, int m,
                                               const int* __restrict__ blkSum,
                                               int* __restrict__ rowptr)
{
    __shared__ int ts[256];
    const int tid = threadIdx.x;
    const int base = blockIdx.x * 2048 + tid * 8;
    int v[8];
    int s = 0;
#pragma unroll
    for (int i = 0; i < 8; ++i) {
        int idx = base + i;
        int x = (idx < m) ? deg[idx] : 0;
        v[i] = s;           // exclusive prefix within thread
        s += x;
    }
    ts[tid] = s;
    __syncthreads();
    for (int off = 1; off < 256; off <<= 1) {
        int u = (tid >= off) ? ts[tid - off] : 0;
        __syncthreads();
        ts[tid] += u;
        __syncthreads();
    }
    const int goff = blkSum[blockIdx.x] + ts[tid] - s;
#pragma unroll
    for (int i = 0; i < 8; ++i) {
        int idx = base + i;
        if (idx < m) rowptr[idx] = goff + v[i];
    }
}

template <int MODE>
__global__ void scatter_k(const int* __restrict__ ei, int E,
                          const int* __restrict__ rowptr, int* __restrict__ cursor,
                          int* __restrict__ srcidx, int* __restrict__ gidx,
                          const int* __restrict__ eai, const float* __restrict__ eaf)
{
    int i = blockIdx.x * 256 + threadIdx.x;
    if (i < E) {
        int d = ei[E + i];
        int pos = rowptr[d] + atomicAdd(&cursor[d], 1);
        srcidx[pos] = ei[i];
        if (MODE == 1) gidx[pos] = eai[2 * i] * 5 + eai[2 * i + 1];
        if (MODE == 2) gidx[pos] = eai[i];
        if (MODE == 3) {
            const float* f = eaf + (size_t)3 * i;
            int i0 = (int)__builtin_fmaf(f[0], 16.f, 0.5f);
            int i1 = (int)__builtin_fmaf(f[1], 16.f, 0.5f);
            int i2 = (int)__builtin_fmaf(f[2], 16.f, 0.5f);
            gidx[pos] = (i0 * NG + i1) * NG + i2;
        }
    }
}

// ---------------------------------------------------------------------------
// Destination-major aggregation (bf16 proj, fp32 gate tables, fp32 out)
// GATED: 0 = no gate (gg), 1 = fp32 gate table indexed by gidx (cg/cp/ce)
// ADDIN: rmw aggr row.
// 4-wide predicated unroll: 4 independent Psrc gathers in flight per wave.
// ---------------------------------------------------------------------------
template <int GATED, int ADDIN>
__global__ __launch_bounds__(256) void dest_aggr(
    const u16* __restrict__ Psrc, const u16* __restrict__ Pdst,
    const int* __restrict__ srcidx, const int* __restrict__ gidx,
    const int* __restrict__ rowptr, const float* __restrict__ gate,
    float* __restrict__ aggr, int n_dst)
{
    const int d = blockIdx.x * 4 + (threadIdx.x >> 6);
    if (d >= n_dst) return;
    const int lane = threadIdx.x & 63;
    const int js = rowptr[d], je = rowptr[d + 1];
    const float4 dv = ld_bf4(Pdst + (size_t)d * CD + lane * 4);   // issued early
    float4 accS = {0.f, 0.f, 0.f, 0.f};
    float4 accG = {0.f, 0.f, 0.f, 0.f};
    const int jn = je - 1;
    for (int j = js; j < je; j += 4) {
        const int j1 = (j + 1 > jn) ? jn : j + 1;
        const int j2 = (j + 2 > jn) ? jn : j + 2;
        const int j3 = (j + 3 > jn) ? jn : j + 3;
        const float m1 = (j + 1 <= jn) ? 1.f : 0.f;
        const float m2 = (j + 2 <= jn) ? 1.f : 0.f;
        const float m3 = (j + 3 <= jn) ? 1.f : 0.f;
        const int s0 = srcidx[j], s1 = srcidx[j1], s2 = srcidx[j2], s3 = srcidx[j3];
        float4 a0 = ld_bf4(Psrc + (size_t)s0 * CD + lane * 4);
        float4 a1 = ld_bf4(Psrc + (size_t)s1 * CD + lane * 4);
        float4 a2 = ld_bf4(Psrc + (size_t)s2 * CD + lane * 4);
        float4 a3 = ld_bf4(Psrc + (size_t)s3 * CD + lane * 4);
        if (GATED) {
            const int g0 = gidx[j], g1 = gidx[j1], g2 = gidx[j2], g3 = gidx[j3];
            float4 q0 = *(const float4*)(gate + (size_t)g0 * CD + lane * 4);
            float4 q1 = *(const float4*)(gate + (size_t)g1 * CD + lane * 4);
            float4 q2 = *(const float4*)(gate + (size_t)g2 * CD + lane * 4);
            float4 q3 = *(const float4*)(gate + (size_t)g3 * CD + lane * 4);
            q1.x *= m1; q1.y *= m1; q1.z *= m1; q1.w *= m1;
            q2.x *= m2; q2.y *= m2; q2.z *= m2; q2.w *= m2;
            q3.x *= m3; q3.y *= m3; q3.z *= m3; q3.w *= m3;
            accS.x += q0.x * a0.x + q1.x * a1.x + q2.x * a2.x + q3.x * a3.x;
            accS.y += q0.y * a0.y + q1.y * a1.y + q2.y * a2.y + q3.y * a3.y;
            accS.z += q0.z * a0.z + q1.z * a1.z + q2.z * a2.z + q3.z * a3.z;
            accS.w += q0.w * a0.w + q1.w * a1.w + q2.w * a2.w + q3.w * a3.w;
            accG.x += q0.x + q1.x + q2.x + q3.x;
            accG.y += q0.y + q1.y + q2.y + q3.y;
            accG.z += q0.z + q1.z + q2.z + q3.z;
            accG.w += q0.w + q1.w + q2.w + q3.w;
        } else {
            accS.x += a0.x + m1 * a1.x + m2 * a2.x + m3 * a3.x;
            accS.y += a0.y + m1 * a1.y + m2 * a2.y + m3 * a3.y;
            accS.z += a0.z + m1 * a1.z + m2 * a2.z + m3 * a3.z;
            accS.w += a0.w + m1 * a1.w + m2 * a2.w + m3 * a3.w;
        }
    }
    const float cnt = (float)(je - js);
    float4 r;
    if (GATED) {
        r.x = accS.x + accG.x * dv.x; r.y = accS.y + accG.y * dv.y;
        r.z = accS.z + accG.z * dv.z; r.w = accS.w + accG.w * dv.w;
    } else {
        r.x = accS.x + cnt * dv.x; r.y = accS.y + cnt * dv.y;
        r.z = accS.z + cnt * dv.z; r.w = accS.w + cnt * dv.w;
    }
    float* ap = aggr + (size_t)d * CD + lane * 4;
    if (ADDIN) {
        float4 old = *(const float4*)ap;
        r.x += old.x; r.y += old.y; r.z += old.z; r.w += old.w;
    }
    *(float4*)ap = r;
}

// ---------------------------------------------------------------------------
extern "C" void kernel_launch(void* const* d_in, const int* in_sizes, int n_in,
                              void* d_out, int out_size, void* d_ws, size_t ws_size,
                              hipStream_t stream)
{
    const float* x_chem = (const float*)d_in[0];
    const float* x_gene = (const float*)d_in[1];
    const float* x_go   = (const float*)d_in[2];
    const float* x_pw   = (const float*)d_in[3];
    const int*   ei_cg  = (const int*)d_in[4];
    const int*   ei_cp  = (const int*)d_in[5];
    const int*   ei_ce  = (const int*)d_in[6];
    const int*   ei_gg  = (const int*)d_in[7];
    const int*   ea_cg  = (const int*)d_in[8];
    const int*   ea_cp  = (const int*)d_in[9];
    const float* ea_ce  = (const float*)d_in[10];

    const float* W_src_cg = (const float*)d_in[11];
    const float* b_src_cg = (const float*)d_in[12];
    const float* W_dst_cg = (const float*)d_in[13];
    const float* b_dst_cg = (const float*)d_in[14];
    const float* W_src_cp = (const float*)d_in[16];
    const float* b_src_cp = (const float*)d_in[17];
    const float* W_dst_cp = (const float*)d_in[18];
    const float* b_dst_cp = (const float*)d_in[19];
    const float* W_src_ce = (const float*)d_in[21];
    const float* b_src_ce = (const float*)d_in[22];
    const float* W_dst_ce = (const float*)d_in[23];
    const float* b_dst_ce = (const float*)d_in[24];
    const float* W_src_gg = (const float*)d_in[26];
    const float* b_src_gg = (const float*)d_in[27];
    const float* W_dst_gg = (const float*)d_in[28];
    const float* b_dst_gg = (const float*)d_in[29];

    const float* emb_at   = (const float*)d_in[31];
    const float* emb_as   = (const float*)d_in[32];
    const float* W_gate_cg = (const float*)d_in[33];
    const float* b_gate_cg = (const float*)d_in[34];
    const float* emb_ph   = (const float*)d_in[35];
    const float* W_gate_cp = (const float*)d_in[36];
    const float* b_gate_cp = (const float*)d_in[37];
    const float* W_gate1_ce = (const float*)d_in[38];
    const float* b_gate1_ce = (const float*)d_in[39];
    const float* W_gate2_ce = (const float*)d_in[40];
    const float* b_gate2_ce = (const float*)d_in[41];
    const float* W_out_gene = (const float*)d_in[42];
    const float* b_out_gene = (const float*)d_in[43];
    const float* W_out_go   = (const float*)d_in[44];
    const float* b_out_go   = (const float*)d_in[45];
    const float* W_out_pw   = (const float*)d_in[46];
    const float* b_out_pw   = (const float*)d_in[47];

    const int Nc  = in_sizes[0] / CD;
    const int Ng  = in_sizes[1] / CD;
    const int Ngo = in_sizes[2] / CD;
    const int Np  = in_sizes[3] / CD;
    const int E   = in_sizes[4] / 2;

    // ---- workspace layout (float units) ----
    float* ws = (float*)d_ws;
    size_t off = 0;
    float* aggr_gene = ws + off; off += (size_t)Ng  * CD;
    float* aggr_go   = ws + off; off += (size_t)Ngo * CD;
    float* aggr_pw   = ws + off; off += (size_t)Np  * CD;   // aggr_* contiguous
    int maxSrc = (Nc > Ng) ? Nc : Ng;
    int maxDst = Ng; if (Ngo > maxDst) maxDst = Ngo; if (Np > maxDst) maxDst = Np;
    u16* projb_src = (u16*)(ws + off); off += (size_t)maxSrc * CD / 2;
    u16* projb_dst = (u16*)(ws + off); off += (size_t)maxDst * CD / 2;
    u16* wt_all    = (u16*)(ws + off); off += (size_t)12 * CD * CD / 2;
    float* gtab_cg = ws + off; off += 50 * CD;
    float* gtab_cp = ws + off; off += 3 * CD;
    float* gtab_ce = ws + off; off += (size_t)NG3 * CD;     // 4913 x 256 fp32 (5 MB)
    float* Hbuf    = ws + off; off += (size_t)NG3 * CD;     // gelu hidden for table build
    // CSR ints (+ CSR-ordered srcidx/gidx + scan block sums)
    int* deg    = (int*)(ws + off);
    int* cursor = deg + (maxDst + 1);
    int* rowptr = cursor + (maxDst + 1);
    int* srcidx = rowptr + (maxDst + 2);
    int* gidx   = srcidx + E;
    int* blkSum = gidx + E;
    {
        size_t ints = 2 * (size_t)(maxDst + 1) + (size_t)(maxDst + 2) + 2 * (size_t)E + 64;
        off += (ints + 3) & ~(size_t)3;
    }

    float* out_gene = (float*)d_out + (size_t)Nc * CD;
    float* out_go   = out_gene + (size_t)Ng * CD;
    float* out_pw   = out_go + (size_t)Ngo * CD;

    const int EB = (E + 255) / 256;

    auto gemm_bf = [&](const float* A, const u16* Wt, const float* b, u16* Y, int N) {
        gemm_mfma<1, 0><<<(N + 31) / 32, 256, 0, stream>>>(A, Wt, b, nullptr, Y, N, 1.0f);
    };
    auto gemm_f = [&](const float* A, const u16* Wt, const float* b, float* Y, int N, float alpha) {
        gemm_mfma<0, 0><<<(N + 31) / 32, 256, 0, stream>>>(A, Wt, b, Y, nullptr, N, alpha);
    };
    auto build_csr = [&](const int* ei, int n_dst, int mode, const int* eai, const float* eaf) {
        hipMemsetAsync(deg, 0, 2 * (size_t)(maxDst + 1) * sizeof(int), stream);
        hist_k<<<EB, 256, 0, stream>>>(ei, E, deg);
        const int m = n_dst + 1;
        const int nblk = (m + 2047) / 2048;
        scan1_k<<<nblk, 256, 0, stream>>>(deg, m, blkSum);
        scan2_k<<<1, 64, 0, stream>>>(blkSum, nblk);
        scan3_k<<<nblk, 256, 0, stream>>>(deg, m, blkSum, rowptr);
        if (mode == 1)
            scatter_k<1><<<EB, 256, 0, stream>>>(ei, E, rowptr, cursor, srcidx, gidx, eai, nullptr);
        else if (mode == 2)
            scatter_k<2><<<EB, 256, 0, stream>>>(ei, E, rowptr, cursor, srcidx, gidx, eai, nullptr);
        else if (mode == 3)
            scatter_k<3><<<EB, 256, 0, stream>>>(ei, E, rowptr, cursor, srcidx, gidx, nullptr, eaf);
        else
            scatter_k<0><<<EB, 256, 0, stream>>>(ei, E, rowptr, cursor, srcidx, nullptr, nullptr, nullptr);
    };

    // 1) passthrough copy
    hipMemcpyAsync(d_out, x_chem, (size_t)Nc * CD * sizeof(float),
                   hipMemcpyDeviceToDevice, stream);

    // 2) weight transpose+convert (12 C x C matrices -> bf16 Wt[n][k])
    u16* Wt_src_cg = wt_all + 0 * CD * CD;  u16* Wt_dst_cg = wt_all + 1 * CD * CD;
    u16* Wt_src_cp = wt_all + 2 * CD * CD;  u16* Wt_dst_cp = wt_all + 3 * CD * CD;
    u16* Wt_src_ce = wt_all + 4 * CD * CD;  u16* Wt_dst_ce = wt_all + 5 * CD * CD;
    u16* Wt_src_gg = wt_all + 6 * CD * CD;  u16* Wt_dst_gg = wt_all + 7 * CD * CD;
    u16* Wt_g2_ce  = wt_all + 8 * CD * CD;
    u16* Wt_o_gene = wt_all + 9 * CD * CD;  u16* Wt_o_go = wt_all + 10 * CD * CD;
    u16* Wt_o_pw   = wt_all + 11 * CD * CD;
    {
        WtArgs wa;
        const float* s[12] = {W_src_cg, W_dst_cg, W_src_cp, W_dst_cp, W_src_ce, W_dst_ce,
                              W_src_gg, W_dst_gg, W_gate2_ce, W_out_gene, W_out_go, W_out_pw};
        u16* dpt[12] = {Wt_src_cg, Wt_dst_cg, Wt_src_cp, Wt_dst_cp, Wt_src_ce, Wt_dst_ce,
                        Wt_src_gg, Wt_dst_gg, Wt_g2_ce, Wt_o_gene, Wt_o_go, Wt_o_pw};
        for (int i = 0; i < 12; ++i) { wa.src[i] = s[i]; wa.dst[i] = dpt[i]; }
        wtrans_k<<<dim3(16, 12), 256, 0, stream>>>(wa);
    }

    // 3) gate tables: cg (50 rows), cp (3 rows), ce (17^3 grid of the
    //    continuous-attr MLP; edges snap to nearest grid point at scatter).
    gate_cg_table_k<<<50, 256, 0, stream>>>(emb_at, emb_as, W_gate_cg, b_gate_cg, gtab_cg);
    gate_cp_table_k<<<3, 256, 0, stream>>>(emb_ph, W_gate_cp, b_gate_cp, gtab_cp);
    build_h_ce_k<<<NG3, 256, 0, stream>>>(W_gate1_ce, b_gate1_ce, Hbuf);
    gemm_mfma<0, 1><<<(NG3 + 31) / 32, 256, 0, stream>>>(Hbuf, Wt_g2_ce, b_gate2_ce,
                                                         gtab_ce, nullptr, NG3, 1.0f);

    // 4) cg: chemical -> gene (store into aggr_gene)
    gemm_bf(x_chem, Wt_src_cg, b_src_cg, projb_src, Nc);
    gemm_bf(x_gene, Wt_dst_cg, b_dst_cg, projb_dst, Ng);
    build_csr(ei_cg, Ng, 1, ea_cg, nullptr);
    dest_aggr<1, 0><<<(Ng + 3) / 4, 256, 0, stream>>>(projb_src, projb_dst, srcidx, gidx,
                                                      rowptr, gtab_cg, aggr_gene, Ng);

    // 5) cp: chemical -> go_term
    gemm_bf(x_chem, Wt_src_cp, b_src_cp, projb_src, Nc);
    gemm_bf(x_go,   Wt_dst_cp, b_dst_cp, projb_dst, Ngo);
    build_csr(ei_cp, Ngo, 2, ea_cp, nullptr);
    dest_aggr<1, 0><<<(Ngo + 3) / 4, 256, 0, stream>>>(projb_src, projb_dst, srcidx, gidx,
                                                       rowptr, gtab_cp, aggr_go, Ngo);

    // 6) ce: chemical -> pathway — now identical pipeline to cg/cp, gated by
    //    the precomputed 17^3 table (no per-edge MLP, no 200 MB G traffic).
    gemm_bf(x_chem, Wt_src_ce, b_src_ce, projb_src, Nc);
    gemm_bf(x_pw,   Wt_dst_ce, b_dst_ce, projb_dst, Np);
    build_csr(ei_ce, Np, 3, nullptr, ea_ce);
    dest_aggr<1, 0><<<(Np + 3) / 4, 256, 0, stream>>>(projb_src, projb_dst, srcidx, gidx,
                                                      rowptr, gtab_ce, aggr_pw, Np);

    // 7) gg: gene -> gene (no gate), read-add-store into aggr_gene
    gemm_bf(x_gene, Wt_src_gg, b_src_gg, projb_src, Ng);
    gemm_bf(x_gene, Wt_dst_gg, b_dst_gg, projb_dst, Ng);
    build_csr(ei_gg, Ng, 0, nullptr, nullptr);
    dest_aggr<0, 1><<<(Ng + 3) / 4, 256, 0, stream>>>(projb_src, projb_dst, srcidx, nullptr,
                                                      rowptr, nullptr, aggr_gene, Ng);

    // 8) output heads straight from fp32 aggr (alpha folds attention 0.25; gene
    //    branch additionally has the 0.5 from 0.5*(aggr_cg+aggr_gg))
    gemm_f(aggr_gene, Wt_o_gene, b_out_gene, out_gene, Ng,  0.125f);
    gemm_f(aggr_go,   Wt_o_go,   b_out_go,   out_go,   Ngo, 0.25f);
    gemm_f(aggr_pw,   Wt_o_pw,   b_out_pw,   out_pw,   Np,  0.25f);
}

// Round 7
// 565.921 us; speedup vs baseline: 1.4254x; 1.2067x over previous
//
#include <hip/hip_runtime.h>
#include <math.h>

#define CD 256
#define NG 17            // ce gate grid points per axis (step 1/16)
#define NG3 (NG * NG * NG)

typedef unsigned short u16;
typedef __attribute__((ext_vector_type(8))) short short8;
typedef __attribute__((ext_vector_type(4))) float f32x4;

// Fast sigmoid: native v_exp_f32 (__expf) + v_rcp_f32.
__device__ __forceinline__ float sigmoidf_(float x) {
    return __builtin_amdgcn_rcpf(1.0f + __expf(-x));
}
// Fast gelu (exact erf formulation): Abramowitz-Stegun 7.1.26 rational
// approx, |eps|<=1.5e-7, native exp/rcp.
__device__ __forceinline__ float geluf_(float x) {
    float z = fabsf(x) * 0.70710678118654752f;       // |x|/sqrt(2)
    float t = __builtin_amdgcn_rcpf(__builtin_fmaf(0.3275911f, z, 1.0f));
    float p = t * __builtin_fmaf(t,
                  __builtin_fmaf(t,
                    __builtin_fmaf(t,
                      __builtin_fmaf(t, 1.061405429f, -1.453152027f),
                      1.421413741f),
                    -0.284496736f),
                  0.254829592f);
    float e = __expf(-z * z);
    float erfz = __builtin_fmaf(-p, e, 1.0f);         // erf(|x|/sqrt2) in [0,1)
    float s = (x < 0.0f) ? -erfz : erfz;
    return 0.5f * x * (1.0f + s);
}

__device__ __forceinline__ u16 f2bf(float x) {
    union { float f; unsigned u; } v; v.f = x;
    unsigned r = v.u + 0x7FFF + ((v.u >> 16) & 1);   // RNE
    return (u16)(r >> 16);
}
__device__ __forceinline__ float bf2f(u16 h) {
    union { unsigned u; float f; } v; v.u = ((unsigned)h) << 16;
    return v.f;
}
__device__ __forceinline__ float4 ld_bf4(const u16* p) {
    ushort4 u = *(const ushort4*)p;
    float4 f; f.x = bf2f(u.x); f.y = bf2f(u.y); f.z = bf2f(u.z); f.w = bf2f(u.w);
    return f;
}
__device__ __forceinline__ ushort4 pk_bf4(float4 v) {
    ushort4 u; u.x = f2bf(v.x); u.y = f2bf(v.y); u.z = f2bf(v.z); u.w = f2bf(v.w);
    return u;
}

// ---------------------------------------------------------------------------
// Batched bf16 MFMA GEMM: for slice s (blockIdx.y):
//   Y[N,256] = alpha*((A [+A2]) @ W) + bias
// A fp32 row-major; Wt bf16 Wt[n][k]=W[k][n] read directly from global (L2).
// One launch covers all independent same-shape GEMMs -> full machine fill
// instead of 8-14 small ramp-bound dispatches. Slices with fewer rows exit
// on row0 >= N. 32-row blocks; wave w owns cols [64w,64w+64).
// ---------------------------------------------------------------------------
struct GemmSlice {
    const float* A; const float* A2; const u16* Wt; const float* bias;
    float* Yf; u16* Yb; int N; float alpha;
};
struct GemmBatch { GemmSlice s[8]; };

template <int OUT_BF16>
__global__ __launch_bounds__(256) void gemm_batch_k(GemmBatch gb)
{
    const GemmSlice S = gb.s[blockIdx.y];
    const int row0 = blockIdx.x * 32;
    if (row0 >= S.N) return;
    __shared__ __align__(16) u16 As[2][32][72];
    const int tid = threadIdx.x;
    const int wave = tid >> 6, lane = tid & 63;
    const int quad = lane >> 4, l16 = lane & 15;
    f32x4 acc[2][4] = {};   // [mi][ni]

    const int r = tid >> 3, seg = tid & 7;      // 32 rows x 8 col-segments
    int gr = row0 + r; if (gr >= S.N) gr = S.N - 1;
    const float* arow = S.A + (size_t)gr * CD;
    const float* a2row = S.A2 ? S.A2 + (size_t)gr * CD : nullptr;

    auto stage = [&](int t) {
        const float* ap = arow + t * 64 + seg * 8;
        float4 v0 = *(const float4*)(ap);
        float4 v1 = *(const float4*)(ap + 4);
        if (a2row) {
            const float* bp = a2row + t * 64 + seg * 8;
            float4 u0 = *(const float4*)(bp);
            float4 u1 = *(const float4*)(bp + 4);
            v0.x += u0.x; v0.y += u0.y; v0.z += u0.z; v0.w += u0.w;
            v1.x += u1.x; v1.y += u1.y; v1.z += u1.z; v1.w += u1.w;
        }
        *(ushort4*)&As[t & 1][r][seg * 8 + 0] = pk_bf4(v0);
        *(ushort4*)&As[t & 1][r][seg * 8 + 4] = pk_bf4(v1);
    };

    stage(0);
    __syncthreads();
#pragma unroll
    for (int t = 0; t < 4; ++t) {
        if (t < 3) stage(t + 1);
        const u16* wb = S.Wt + (size_t)(wave * 64 + l16) * CD + t * 64 + quad * 8;
#pragma unroll
        for (int ks = 0; ks < 64; ks += 32) {
            short8 af[2], bf[4];
#pragma unroll
            for (int mi = 0; mi < 2; ++mi)
                af[mi] = *(const short8*)&As[t & 1][mi * 16 + l16][ks + quad * 8];
#pragma unroll
            for (int ni = 0; ni < 4; ++ni)
                bf[ni] = *(const short8*)(wb + (size_t)(ni * 16) * CD + ks);
#pragma unroll
            for (int mi = 0; mi < 2; ++mi)
#pragma unroll
                for (int ni = 0; ni < 4; ++ni)
                    acc[mi][ni] = __builtin_amdgcn_mfma_f32_16x16x32_bf16(
                        af[mi], bf[ni], acc[mi][ni], 0, 0, 0);
        }
        if (t < 3) __syncthreads();
    }
#pragma unroll
    for (int mi = 0; mi < 2; ++mi)
#pragma unroll
        for (int rr = 0; rr < 4; ++rr) {
            int m = mi * 16 + quad * 4 + rr;
            int grow = row0 + m;
            if (grow < S.N) {
#pragma unroll
                for (int ni = 0; ni < 4; ++ni) {
                    int n = wave * 64 + ni * 16 + l16;
                    float v = S.alpha * acc[mi][ni][rr] + S.bias[n];
                    if (OUT_BF16) S.Yb[(size_t)grow * CD + n] = f2bf(v);
                    else          S.Yf[(size_t)grow * CD + n] = v;
                }
            }
        }
}

// Single-slice variant kept for the ce gate-table build (sigmoid epilogue).
template <int OUT_BF16, int ACT>
__global__ __launch_bounds__(256) void gemm_mfma(
    const float* __restrict__ A, const u16* __restrict__ Wt,
    const float* __restrict__ bias, float* __restrict__ Yf, u16* __restrict__ Yb,
    int N, float alpha)
{
    __shared__ __align__(16) u16 As[2][32][72];
    const int tid = threadIdx.x;
    const int row0 = blockIdx.x * 32;
    const int wave = tid >> 6, lane = tid & 63;
    const int quad = lane >> 4, l16 = lane & 15;
    f32x4 acc[2][4] = {};

    const int r = tid >> 3, seg = tid & 7;
    int gr = row0 + r; if (gr >= N) gr = N - 1;
    const float* arow = A + (size_t)gr * CD;

    auto stage = [&](int t) {
        const float* ap = arow + t * 64 + seg * 8;
        float4 v0 = *(const float4*)(ap);
        float4 v1 = *(const float4*)(ap + 4);
        *(ushort4*)&As[t & 1][r][seg * 8 + 0] = pk_bf4(v0);
        *(ushort4*)&As[t & 1][r][seg * 8 + 4] = pk_bf4(v1);
    };

    stage(0);
    __syncthreads();
#pragma unroll
    for (int t = 0; t < 4; ++t) {
        if (t < 3) stage(t + 1);
        const u16* wb = Wt + (size_t)(wave * 64 + l16) * CD + t * 64 + quad * 8;
#pragma unroll
        for (int ks = 0; ks < 64; ks += 32) {
            short8 af[2], bf[4];
#pragma unroll
            for (int mi = 0; mi < 2; ++mi)
                af[mi] = *(const short8*)&As[t & 1][mi * 16 + l16][ks + quad * 8];
#pragma unroll
            for (int ni = 0; ni < 4; ++ni)
                bf[ni] = *(const short8*)(wb + (size_t)(ni * 16) * CD + ks);
#pragma unroll
            for (int mi = 0; mi < 2; ++mi)
#pragma unroll
                for (int ni = 0; ni < 4; ++ni)
                    acc[mi][ni] = __builtin_amdgcn_mfma_f32_16x16x32_bf16(
                        af[mi], bf[ni], acc[mi][ni], 0, 0, 0);
        }
        if (t < 3) __syncthreads();
    }
#pragma unroll
    for (int mi = 0; mi < 2; ++mi)
#pragma unroll
        for (int rr = 0; rr < 4; ++rr) {
            int m = mi * 16 + quad * 4 + rr;
            int grow = row0 + m;
            if (grow < N) {
#pragma unroll
                for (int ni = 0; ni < 4; ++ni) {
                    int n = wave * 64 + ni * 16 + l16;
                    float v = alpha * acc[mi][ni][rr] + bias[n];
                    if (ACT) v = sigmoidf_(v);
                    if (OUT_BF16) Yb[(size_t)grow * CD + n] = f2bf(v);
                    else          Yf[(size_t)grow * CD + n] = v;
                }
            }
        }
}

// ---------------------------------------------------------------------------
// ce gate table, step 1: H[c,:] = gelu( grid(c) @ W1 + b1 ), fp32. 17^3 rows.
// ---------------------------------------------------------------------------
__global__ __launch_bounds__(256) void build_h_ce_k(
    const float* __restrict__ W1, const float* __restrict__ b1,
    float* __restrict__ H)
{
    const int c = blockIdx.x;
    const int iz = c % NG, iy = (c / NG) % NG, ix = c / (NG * NG);
    const float a0 = ix * 0.0625f, a1 = iy * 0.0625f, a2 = iz * 0.0625f;
    const int j = threadIdx.x;
    float v = __builtin_fmaf(a0, W1[j],
              __builtin_fmaf(a1, W1[CD + j],
              __builtin_fmaf(a2, W1[2 * CD + j], b1[j])));
    H[(size_t)c * CD + j] = geluf_(v);
}

// ---------------------------------------------------------------------------
// Weight transpose+convert: Wt[n][k] = bf16(W[k][n]) for 12 matrices at once.
// ---------------------------------------------------------------------------
struct WtArgs { const float* src[12]; u16* dst[12]; };

__global__ __launch_bounds__(256) void wtrans_k(WtArgs a)
{
    __shared__ float t[64][65];
    const int mat = blockIdx.y;
    const int tile = blockIdx.x;            // 16 tiles of 64x64
    const int tr = tile >> 2, tc = tile & 3;
    const int r = threadIdx.x >> 2, seg = threadIdx.x & 3;
    const float* S = a.src[mat];
    u16* D = a.dst[mat];
#pragma unroll
    for (int i = 0; i < 16; i += 4) {
        float4 v = *(const float4*)(S + (size_t)(tr * 64 + r) * CD + tc * 64 + seg * 16 + i);
        t[r][seg * 16 + i + 0] = v.x;
        t[r][seg * 16 + i + 1] = v.y;
        t[r][seg * 16 + i + 2] = v.z;
        t[r][seg * 16 + i + 3] = v.w;
    }
    __syncthreads();
#pragma unroll
    for (int i = 0; i < 16; ++i)
        D[(size_t)(tc * 64 + r) * CD + tr * 64 + seg * 16 + i] = f2bf(t[seg * 16 + i][r]);
}

// ---------------------------------------------------------------------------
// Gate lookup tables (cg: 50 combos, cp: 3 phenos), fp32
// ---------------------------------------------------------------------------
__global__ void gate_cg_table_k(const float* __restrict__ embA, const float* __restrict__ embB,
                                const float* __restrict__ Wg, const float* __restrict__ bg,
                                float* __restrict__ tab)
{
    int combo = blockIdx.x;
    int a = combo / 5, b = combo % 5;
    int j = threadIdx.x;
    float s = bg[j];
    for (int k = 0; k < 32; ++k) s += embA[a * 32 + k] * Wg[k * CD + j];
    for (int k = 0; k < 32; ++k) s += embB[b * 32 + k] * Wg[(32 + k) * CD + j];
    tab[(size_t)combo * CD + j] = sigmoidf_(s);
}

__global__ void gate_cp_table_k(const float* __restrict__ embP, const float* __restrict__ Wg,
                                const float* __restrict__ bg, float* __restrict__ tab)
{
    int p = blockIdx.x;
    int j = threadIdx.x;
    float s = bg[j];
    for (int k = 0; k < 32; ++k) s += embP[p * 32 + k] * Wg[k * CD + j];
    tab[(size_t)p * CD + j] = sigmoidf_(s);
}

// ---------------------------------------------------------------------------
// Batched CSR construction over 4 edge types (blockIdx.y = type).
// scatter materializes srcidx (source node) and gidx (gate-table row) in
// CSR order. mode: 0 = none (gg), 1 = cg a*5+b, 2 = cp pheno, 3 = ce grid.
// ---------------------------------------------------------------------------
struct CsrSlice {
    const int* ei; int* deg; int* cursor; int* rowptr; int* blkSum;
    int* srcidx; int* gidx; int n_dst; int mode;
    const int* eai; const float* eaf;
};
struct CsrBatch { CsrSlice s[4]; };

__global__ void hist_batch_k(CsrBatch cb, int E)
{
    const CsrSlice S = cb.s[blockIdx.y];
    int i = blockIdx.x * 256 + threadIdx.x;
    if (i < E) atomicAdd(&S.deg[S.ei[E + i]], 1);
}

__global__ __launch_bounds__(256) void scan1_batch_k(CsrBatch cb)
{
    const CsrSlice S = cb.s[blockIdx.y];
    const int m = S.n_dst + 1;
    __shared__ int ts[256];
    const int tid = threadIdx.x;
    const int base = blockIdx.x * 2048 + tid * 8;
    int s = 0;
#pragma unroll
    for (int i = 0; i < 8; ++i) {
        int idx = base + i;
        s += (idx < m) ? S.deg[idx] : 0;
    }
    ts[tid] = s;
    __syncthreads();
    for (int off = 128; off > 0; off >>= 1) {
        if (tid < off) ts[tid] += ts[tid + off];
        __syncthreads();
    }
    if (tid == 0) S.blkSum[blockIdx.x] = ts[0];
}

__global__ __launch_bounds__(64) void scan2_batch_k(CsrBatch cb, int nblk)
{
    const CsrSlice S = cb.s[blockIdx.x];
    __shared__ int ts[64];
    const int tid = threadIdx.x;
    const int o = (tid < nblk) ? S.blkSum[tid] : 0;
    ts[tid] = o;
    __syncthreads();
    for (int off = 1; off < 64; off <<= 1) {
        int u = (tid >= off) ? ts[tid - off] : 0;
        __syncthreads();
        ts[tid] += u;
        __syncthreads();
    }
    if (tid < nblk) S.blkSum[tid] = ts[tid] - o;   // exclusive
}

__global__ __launch_bounds__(256) void scan3_batch_k(CsrBatch cb)
{
    const CsrSlice S = cb.s[blockIdx.y];
    const int m = S.n_dst + 1;
    __shared__ int ts[256];
    const int tid = threadIdx.x;
    const int base = blockIdx.x * 2048 + tid * 8;
    int v[8];
    int s = 0;
#pragma unroll
    for (int i = 0; i < 8; ++i) {
        int idx = base + i;
        int x = (idx < m) ? S.deg[idx] : 0;
        v[i] = s;           // exclusive prefix within thread
        s += x;
    }
    ts[tid] = s;
    __syncthreads();
    for (int off = 1; off < 256; off <<= 1) {
        int u = (tid >= off) ? ts[tid - off] : 0;
        __syncthreads();
        ts[tid] += u;
        __syncthreads();
    }
    const int goff = S.blkSum[blockIdx.x] + ts[tid] - s;
#pragma unroll
    for (int i = 0; i < 8; ++i) {
        int idx = base + i;
        if (idx < m) S.rowptr[idx] = goff + v[i];
    }
}

__global__ void scatter_batch_k(CsrBatch cb, int E)
{
    const CsrSlice S = cb.s[blockIdx.y];
    int i = blockIdx.x * 256 + threadIdx.x;
    if (i < E) {
        int d = S.ei[E + i];
        int pos = S.rowptr[d] + atomicAdd(&S.cursor[d], 1);
        S.srcidx[pos] = S.ei[i];
        if (S.mode == 1) S.gidx[pos] = S.eai[2 * i] * 5 + S.eai[2 * i + 1];
        else if (S.mode == 2) S.gidx[pos] = S.eai[i];
        else if (S.mode == 3) {
            const float* f = S.eaf + (size_t)3 * i;
            int i0 = (int)__builtin_fmaf(f[0], 16.f, 0.5f);
            int i1 = (int)__builtin_fmaf(f[1], 16.f, 0.5f);
            int i2 = (int)__builtin_fmaf(f[2], 16.f, 0.5f);
            S.gidx[pos] = (i0 * NG + i1) * NG + i2;
        }
    }
}

// ---------------------------------------------------------------------------
// Batched destination-major aggregation over 4 edge types (blockIdx.y).
// gated: 1 = fp32 gate table by gidx; 0 = plain (gg). Each type writes its
// own aggr buffer (no cross-type dependencies -> safe to batch).
// 4-wide predicated unroll: 4 independent Psrc gathers in flight per wave.
// ---------------------------------------------------------------------------
struct AggrSlice {
    const u16* Psrc; const u16* Pdst; const int* srcidx; const int* gidx;
    const int* rowptr; const float* gate; float* aggr; int n_dst; int gated;
};
struct AggrBatch { AggrSlice s[4]; };

__global__ __launch_bounds__(256) void aggr_batch_k(AggrBatch ab)
{
    const AggrSlice S = ab.s[blockIdx.y];
    const int d = blockIdx.x * 4 + (threadIdx.x >> 6);
    if (d >= S.n_dst) return;
    const int lane = threadIdx.x & 63;
    const int js = S.rowptr[d], je = S.rowptr[d + 1];
    const float4 dv = ld_bf4(S.Pdst + (size_t)d * CD + lane * 4);   // issued early
    float4 accS = {0.f, 0.f, 0.f, 0.f};
    float4 accG = {0.f, 0.f, 0.f, 0.f};
    const int jn = je - 1;
    for (int j = js; j < je; j += 4) {
        const int j1 = (j + 1 > jn) ? jn : j + 1;
        const int j2 = (j + 2 > jn) ? jn : j + 2;
        const int j3 = (j + 3 > jn) ? jn : j + 3;
        const float m1 = (j + 1 <= jn) ? 1.f : 0.f;
        const float m2 = (j + 2 <= jn) ? 1.f : 0.f;
        const float m3 = (j + 3 <= jn) ? 1.f : 0.f;
        const int s0 = S.srcidx[j], s1 = S.srcidx[j1], s2 = S.srcidx[j2], s3 = S.srcidx[j3];
        float4 a0 = ld_bf4(S.Psrc + (size_t)s0 * CD + lane * 4);
        float4 a1 = ld_bf4(S.Psrc + (size_t)s1 * CD + lane * 4);
        float4 a2 = ld_bf4(S.Psrc + (size_t)s2 * CD + lane * 4);
        float4 a3 = ld_bf4(S.Psrc + (size_t)s3 * CD + lane * 4);
        if (S.gated) {
            const int g0 = S.gidx[j], g1 = S.gidx[j1], g2 = S.gidx[j2], g3 = S.gidx[j3];
            float4 q0 = *(const float4*)(S.gate + (size_t)g0 * CD + lane * 4);
            float4 q1 = *(const float4*)(S.gate + (size_t)g1 * CD + lane * 4);
            float4 q2 = *(const float4*)(S.gate + (size_t)g2 * CD + lane * 4);
            float4 q3 = *(const float4*)(S.gate + (size_t)g3 * CD + lane * 4);
            q1.x *= m1; q1.y *= m1; q1.z *= m1; q1.w *= m1;
            q2.x *= m2; q2.y *= m2; q2.z *= m2; q2.w *= m2;
            q3.x *= m3; q3.y *= m3; q3.z *= m3; q3.w *= m3;
            accS.x += q0.x * a0.x + q1.x * a1.x + q2.x * a2.x + q3.x * a3.x;
            accS.y += q0.y * a0.y + q1.y * a1.y + q2.y * a2.y + q3.y * a3.y;
            accS.z += q0.z * a0.z + q1.z * a1.z + q2.z * a2.z + q3.z * a3.z;
            accS.w += q0.w * a0.w + q1.w * a1.w + q2.w * a2.w + q3.w * a3.w;
            accG.x += q0.x + q1.x + q2.x + q3.x;
            accG.y += q0.y + q1.y + q2.y + q3.y;
            accG.z += q0.z + q1.z + q2.z + q3.z;
            accG.w += q0.w + q1.w + q2.w + q3.w;
        } else {
            accS.x += a0.x + m1 * a1.x + m2 * a2.x + m3 * a3.x;
            accS.y += a0.y + m1 * a1.y + m2 * a2.y + m3 * a3.y;
            accS.z += a0.z + m1 * a1.z + m2 * a2.z + m3 * a3.z;
            accS.w += a0.w + m1 * a1.w + m2 * a2.w + m3 * a3.w;
        }
    }
    const float cnt = (float)(je - js);
    float4 r;
    if (S.gated) {
        r.x = accS.x + accG.x * dv.x; r.y = accS.y + accG.y * dv.y;
        r.z = accS.z + accG.z * dv.z; r.w = accS.w + accG.w * dv.w;
    } else {
        r.x = accS.x + cnt * dv.x; r.y = accS.y + cnt * dv.y;
        r.z = accS.z + cnt * dv.z; r.w = accS.w + cnt * dv.w;
    }
    *(float4*)(S.aggr + (size_t)d * CD + lane * 4) = r;
}

// ---------------------------------------------------------------------------
extern "C" void kernel_launch(void* const* d_in, const int* in_sizes, int n_in,
                              void* d_out, int out_size, void* d_ws, size_t ws_size,
                              hipStream_t stream)
{
    const float* x_chem = (const float*)d_in[0];
    const float* x_gene = (const float*)d_in[1];
    const float* x_go   = (const float*)d_in[2];
    const float* x_pw   = (const float*)d_in[3];
    const int*   ei_cg  = (const int*)d_in[4];
    const int*   ei_cp  = (const int*)d_in[5];
    const int*   ei_ce  = (const int*)d_in[6];
    const int*   ei_gg  = (const int*)d_in[7];
    const int*   ea_cg  = (const int*)d_in[8];
    const int*   ea_cp  = (const int*)d_in[9];
    const float* ea_ce  = (const float*)d_in[10];

    const float* W_src_cg = (const float*)d_in[11];
    const float* b_src_cg = (const float*)d_in[12];
    const float* W_dst_cg = (const float*)d_in[13];
    const float* b_dst_cg = (const float*)d_in[14];
    const float* W_src_cp = (const float*)d_in[16];
    const float* b_src_cp = (const float*)d_in[17];
    const float* W_dst_cp = (const float*)d_in[18];
    const float* b_dst_cp = (const float*)d_in[19];
    const float* W_src_ce = (const float*)d_in[21];
    const float* b_src_ce = (const float*)d_in[22];
    const float* W_dst_ce = (const float*)d_in[23];
    const float* b_dst_ce = (const float*)d_in[24];
    const float* W_src_gg = (const float*)d_in[26];
    const float* b_src_gg = (const float*)d_in[27];
    const float* W_dst_gg = (const float*)d_in[28];
    const float* b_dst_gg = (const float*)d_in[29];

    const float* emb_at   = (const float*)d_in[31];
    const float* emb_as   = (const float*)d_in[32];
    const float* W_gate_cg = (const float*)d_in[33];
    const float* b_gate_cg = (const float*)d_in[34];
    const float* emb_ph   = (const float*)d_in[35];
    const float* W_gate_cp = (const float*)d_in[36];
    const float* b_gate_cp = (const float*)d_in[37];
    const float* W_gate1_ce = (const float*)d_in[38];
    const float* b_gate1_ce = (const float*)d_in[39];
    const float* W_gate2_ce = (const float*)d_in[40];
    const float* b_gate2_ce = (const float*)d_in[41];
    const float* W_out_gene = (const float*)d_in[42];
    const float* b_out_gene = (const float*)d_in[43];
    const float* W_out_go   = (const float*)d_in[44];
    const float* b_out_go   = (const float*)d_in[45];
    const float* W_out_pw   = (const float*)d_in[46];
    const float* b_out_pw   = (const float*)d_in[47];

    const int Nc  = in_sizes[0] / CD;
    const int Ng  = in_sizes[1] / CD;
    const int Ngo = in_sizes[2] / CD;
    const int Np  = in_sizes[3] / CD;
    const int E   = in_sizes[4] / 2;

    // ---- workspace layout (float units) ----
    float* ws = (float*)d_ws;
    size_t off = 0;
    float* aggr_gene = ws + off; off += (size_t)Ng  * CD;
    float* aggr_go   = ws + off; off += (size_t)Ngo * CD;
    float* aggr_pw   = ws + off; off += (size_t)Np  * CD;
    float* aggr_gg   = ws + off; off += (size_t)Ng  * CD;   // gg gets own buffer
    // 8 projection outputs (bf16), disaggregated so all GEMMs batch into one launch
    u16* p_cg_src = (u16*)(ws + off); off += (size_t)Nc  * CD / 2;
    u16* p_cg_dst = (u16*)(ws + off); off += (size_t)Ng  * CD / 2;
    u16* p_cp_src = (u16*)(ws + off); off += (size_t)Nc  * CD / 2;
    u16* p_cp_dst = (u16*)(ws + off); off += (size_t)Ngo * CD / 2;
    u16* p_ce_src = (u16*)(ws + off); off += (size_t)Nc  * CD / 2;
    u16* p_ce_dst = (u16*)(ws + off); off += (size_t)Np  * CD / 2;
    u16* p_gg_src = (u16*)(ws + off); off += (size_t)Ng  * CD / 2;
    u16* p_gg_dst = (u16*)(ws + off); off += (size_t)Ng  * CD / 2;
    u16* wt_all   = (u16*)(ws + off); off += (size_t)12 * CD * CD / 2;
    float* gtab_cg = ws + off; off += 50 * CD;
    float* gtab_cp = ws + off; off += 3 * CD;
    float* gtab_ce = ws + off; off += (size_t)NG3 * CD;     // 4913 x 256 fp32
    float* Hbuf    = ws + off; off += (size_t)NG3 * CD;
    int maxDst = Ng; if (Ngo > maxDst) maxDst = Ngo; if (Np > maxDst) maxDst = Np;
    // Per-type CSR arrays. deg+cursor for all 4 types contiguous -> one memset.
    int* ibase = (int*)(ws + off);
    int* degs[4], *curs[4], *rptrs[4], *bsums[4], *srcs[4], *gixs[4];
    {
        int* p = ibase;
        for (int t = 0; t < 4; ++t) { degs[t] = p; p += maxDst + 1; curs[t] = p; p += maxDst + 1; }
        for (int t = 0; t < 4; ++t) { rptrs[t] = p; p += maxDst + 2; }
        for (int t = 0; t < 4; ++t) { bsums[t] = p; p += 64; }
        for (int t = 0; t < 4; ++t) { srcs[t] = p; p += E; }
        for (int t = 0; t < 4; ++t) { gixs[t] = p; p += E; }
        off += (size_t)(p - ibase + 3) & ~(size_t)3;
    }

    float* out_gene = (float*)d_out + (size_t)Nc * CD;
    float* out_go   = out_gene + (size_t)Ng * CD;
    float* out_pw   = out_go + (size_t)Ngo * CD;

    const int EB = (E + 255) / 256;

    // 1) passthrough copy
    hipMemcpyAsync(d_out, x_chem, (size_t)Nc * CD * sizeof(float),
                   hipMemcpyDeviceToDevice, stream);

    // 2) weight transpose+convert (12 C x C matrices -> bf16 Wt[n][k])
    u16* Wt_src_cg = wt_all + 0 * CD * CD;  u16* Wt_dst_cg = wt_all + 1 * CD * CD;
    u16* Wt_src_cp = wt_all + 2 * CD * CD;  u16* Wt_dst_cp = wt_all + 3 * CD * CD;
    u16* Wt_src_ce = wt_all + 4 * CD * CD;  u16* Wt_dst_ce = wt_all + 5 * CD * CD;
    u16* Wt_src_gg = wt_all + 6 * CD * CD;  u16* Wt_dst_gg = wt_all + 7 * CD * CD;
    u16* Wt_g2_ce  = wt_all + 8 * CD * CD;
    u16* Wt_o_gene = wt_all + 9 * CD * CD;  u16* Wt_o_go = wt_all + 10 * CD * CD;
    u16* Wt_o_pw   = wt_all + 11 * CD * CD;
    {
        WtArgs wa;
        const float* s[12] = {W_src_cg, W_dst_cg, W_src_cp, W_dst_cp, W_src_ce, W_dst_ce,
                              W_src_gg, W_dst_gg, W_gate2_ce, W_out_gene, W_out_go, W_out_pw};
        u16* dpt[12] = {Wt_src_cg, Wt_dst_cg, Wt_src_cp, Wt_dst_cp, Wt_src_ce, Wt_dst_ce,
                        Wt_src_gg, Wt_dst_gg, Wt_g2_ce, Wt_o_gene, Wt_o_go, Wt_o_pw};
        for (int i = 0; i < 12; ++i) { wa.src[i] = s[i]; wa.dst[i] = dpt[i]; }
        wtrans_k<<<dim3(16, 12), 256, 0, stream>>>(wa);
    }

    // 3) gate tables: cg (50), cp (3), ce (17^3 grid; edges snap at scatter)
    gate_cg_table_k<<<50, 256, 0, stream>>>(emb_at, emb_as, W_gate_cg, b_gate_cg, gtab_cg);
    gate_cp_table_k<<<3, 256, 0, stream>>>(emb_ph, W_gate_cp, b_gate_cp, gtab_cp);
    build_h_ce_k<<<NG3, 256, 0, stream>>>(W_gate1_ce, b_gate1_ce, Hbuf);
    gemm_mfma<0, 1><<<(NG3 + 31) / 32, 256, 0, stream>>>(Hbuf, Wt_g2_ce, b_gate2_ce,
                                                         gtab_ce, nullptr, NG3, 1.0f);

    // 4) ALL 8 projection GEMMs in one launch (independent; separate outputs)
    {
        GemmBatch gb;
        const float* As[8]  = {x_chem, x_gene, x_chem, x_go, x_chem, x_pw, x_gene, x_gene};
        const u16* Ws[8]    = {Wt_src_cg, Wt_dst_cg, Wt_src_cp, Wt_dst_cp,
                               Wt_src_ce, Wt_dst_ce, Wt_src_gg, Wt_dst_gg};
        const float* bs[8]  = {b_src_cg, b_dst_cg, b_src_cp, b_dst_cp,
                               b_src_ce, b_dst_ce, b_src_gg, b_dst_gg};
        u16* Ys[8]          = {p_cg_src, p_cg_dst, p_cp_src, p_cp_dst,
                               p_ce_src, p_ce_dst, p_gg_src, p_gg_dst};
        int  Ns[8]          = {Nc, Ng, Nc, Ngo, Nc, Np, Ng, Ng};
        int maxN = 0;
        for (int i = 0; i < 8; ++i) {
            gb.s[i] = {As[i], nullptr, Ws[i], bs[i], nullptr, Ys[i], Ns[i], 1.0f};
            if (Ns[i] > maxN) maxN = Ns[i];
        }
        gemm_batch_k<1><<<dim3((maxN + 31) / 32, 8), 256, 0, stream>>>(gb);
    }

    // 5) ALL 4 CSR builds batched (one memset + 5 batched kernels)
    CsrBatch cb;
    {
        const int* eis[4]  = {ei_cg, ei_cp, ei_ce, ei_gg};
        int   nds[4]       = {Ng, Ngo, Np, Ng};
        int   modes[4]     = {1, 2, 3, 0};
        const int* eais[4] = {ea_cg, ea_cp, nullptr, nullptr};
        const float* eafs[4] = {nullptr, nullptr, ea_ce, nullptr};
        for (int t = 0; t < 4; ++t)
            cb.s[t] = {eis[t], degs[t], curs[t], rptrs[t], bsums[t],
                       srcs[t], gixs[t], nds[t], modes[t], eais[t], eafs[t]};
        hipMemsetAsync(degs[0], 0, 8 * (size_t)(maxDst + 1) * sizeof(int), stream);
        const int nblk = (maxDst + 1 + 2047) / 2048;
        hist_batch_k<<<dim3(EB, 4), 256, 0, stream>>>(cb, E);
        scan1_batch_k<<<dim3(nblk, 4), 256, 0, stream>>>(cb);
        scan2_batch_k<<<4, 64, 0, stream>>>(cb, nblk);
        scan3_batch_k<<<dim3(nblk, 4), 256, 0, stream>>>(cb);
        scatter_batch_k<<<dim3(EB, 4), 256, 0, stream>>>(cb, E);
    }

    // 6) ALL 4 aggregations in one launch (each type -> own aggr buffer)
    {
        AggrBatch ab;
        ab.s[0] = {p_cg_src, p_cg_dst, srcs[0], gixs[0], rptrs[0], gtab_cg, aggr_gene, Ng,  1};
        ab.s[1] = {p_cp_src, p_cp_dst, srcs[1], gixs[1], rptrs[1], gtab_cp, aggr_go,   Ngo, 1};
        ab.s[2] = {p_ce_src, p_ce_dst, srcs[2], gixs[2], rptrs[2], gtab_ce, aggr_pw,   Np,  1};
        ab.s[3] = {p_gg_src, p_gg_dst, srcs[3], nullptr, rptrs[3], nullptr, aggr_gg,   Ng,  0};
        int maxD = Ng; // >= Ngo, Np
        aggr_batch_k<<<dim3((maxD + 3) / 4, 4), 256, 0, stream>>>(ab);
    }

    // 7) output heads in one launch; gene slice sums aggr_cg + aggr_gg during
    //    staging (replaces the old ADDIN pass). alpha folds attention 0.25
    //    (+0.5 for gene).
    {
        GemmBatch gb;
        gb.s[0] = {aggr_gene, aggr_gg, Wt_o_gene, b_out_gene, out_gene, nullptr, Ng,  0.125f};
        gb.s[1] = {aggr_go,   nullptr, Wt_o_go,   b_out_go,   out_go,   nullptr, Ngo, 0.25f};
        gb.s[2] = {aggr_pw,   nullptr, Wt_o_pw,   b_out_pw,   out_pw,   nullptr, Np,  0.25f};
        for (int i = 3; i < 8; ++i) gb.s[i] = {nullptr, nullptr, nullptr, nullptr,
                                               nullptr, nullptr, 0, 0.f};
        gemm_batch_k<0><<<dim3((Ng + 31) / 32, 3), 256, 0, stream>>>(gb);
    }
}